// Round 1
// baseline (866.401 us; speedup 1.0000x reference)
//
#include <hip/hip_runtime.h>
#include <math.h>

namespace {

constexpr int NBATCH = 16;
constexpr int NCH    = 21;
constexpr int HH     = 41;
constexpr int NP     = HH * HH;       // 1681 pixels
constexpr int IW     = 321;           // input image H=W
constexpr int QS     = 32;            // padded channel stride for P/LOGU/Q
constexpr float EPSV = 1e-5f;

constexpr int ITILES = (NP + 63) / 64;          // 27
constexpr int NPIX   = NBATCH * NP;             // 26896
constexpr int LOSS_BLOCKS = (NPIX + 255) / 256; // 106

// workspace offsets in floats (each 64-float aligned)
constexpr size_t OFF_W    = 0;                  // 41*321 = 13161
constexpr size_t OFF_COL  = 13184;              // colors [16][1681][4]
constexpr size_t OFF_P    = OFF_COL + 107584;   // probs  [16][1681][32]
constexpr size_t OFF_LOGU = OFF_P   + 860672;   // log(probs)
constexpr size_t OFF_QA   = OFF_LOGU + 860672;  // Q ping
constexpr size_t OFF_QB   = OFF_QA  + 860672;   // Q pong
constexpr size_t OFF_RSG  = OFF_QB  + 860672;   // 1/sqrt(sg) [1681]
constexpr size_t OFF_RSB  = OFF_RSG + 1728;     // 1/sqrt(sb) [16*1681]
constexpr size_t OFF_PART = OFF_RSB + 27008;    // loss partials
constexpr size_t OFF_M    = OFF_PART + 256;     // M [16][1681][1681] = 45,212,176 floats
// total ~195.3 MB

__device__ __forceinline__ float wave_sum(float v) {
  #pragma unroll
  for (int off = 32; off > 0; off >>= 1) v += __shfl_down(v, off, 64);
  return v;
}

// K1: jax.image.resize 'linear' (antialias=True) weight matrix, 321 -> 41.
// w[o][i] = max(0, 1 - |s_o - i|/inv) / colsum,  s_o = (o+0.5)*inv - 0.5, inv = 321/41.
__global__ void k_weights(float* __restrict__ W) {
  int o = threadIdx.x;
  if (o >= HH) return;
  const float inv = (float)IW / (float)HH;
  float s = (o + 0.5f) * inv - 0.5f;
  float tot = 0.f;
  for (int i = 0; i < IW; ++i) {
    float x = fabsf(s - (float)i) / inv;
    tot += fmaxf(0.f, 1.f - x);
  }
  float r = 1.f / tot;
  for (int i = 0; i < IW; ++i) {
    float x = fabsf(s - (float)i) / inv;
    W[o * IW + i] = fmaxf(0.f, 1.f - x) * r;
  }
}

// K2: filtered resize of images (16,3,321,321) -> colors [n][p][4] at 41x41
__global__ void k_resize(const float* __restrict__ img, const float* __restrict__ W,
                         float* __restrict__ colors) {
  int t = blockIdx.x * blockDim.x + threadIdx.x;
  if (t >= NPIX) return;
  int nb = t / NP, p = t % NP;
  int yo = p / HH, xo = p % HH;
  const float inv = (float)IW / (float)HH;
  float sy = (yo + 0.5f) * inv - 0.5f;
  float sx = (xo + 0.5f) * inv - 0.5f;
  int ylo = max(0, (int)ceilf(sy - inv)), yhi = min(IW - 1, (int)floorf(sy + inv));
  int xlo = max(0, (int)ceilf(sx - inv)), xhi = min(IW - 1, (int)floorf(sx + inv));
  float a0 = 0.f, a1 = 0.f, a2 = 0.f;
  for (int iy = ylo; iy <= yhi; ++iy) {
    float wy = W[yo * IW + iy];
    const float* base = img + ((size_t)nb * 3 * IW + iy) * IW;
    float r0 = 0.f, r1 = 0.f, r2 = 0.f;
    for (int ix = xlo; ix <= xhi; ++ix) {
      float wx = W[xo * IW + ix];
      r0 += wx * base[ix];
      r1 += wx * base[(size_t)IW * IW + ix];
      r2 += wx * base[2 * (size_t)IW * IW + ix];
    }
    a0 += wy * r0; a1 += wy * r1; a2 += wy * r2;
  }
  float* c = colors + (size_t)t * 4;
  c[0] = a0; c[1] = a1; c[2] = a2; c[3] = 0.f;
}

// K3: clamped channel softmax of predict -> P, LOGU (padded [n][i][32])
__global__ void k_probs(const float* __restrict__ pred, float* __restrict__ P,
                        float* __restrict__ LOGU) {
  int t = blockIdx.x * blockDim.x + threadIdx.x;
  if (t >= NPIX) return;
  int nb = t / NP, i = t % NP;
  const float* src = pred + (size_t)nb * NCH * NP + i;
  float v[NCH];
  float m = -1e30f;
  #pragma unroll
  for (int c = 0; c < NCH; ++c) { v[c] = src[(size_t)c * NP]; m = fmaxf(m, v[c]); }
  float s = 0.f;
  #pragma unroll
  for (int c = 0; c < NCH; ++c) { v[c] = expf(v[c] - m); s += v[c]; }
  float r = 1.f / s;
  float s2 = 0.f;
  #pragma unroll
  for (int c = 0; c < NCH; ++c) { v[c] = fminf(fmaxf(v[c] * r, EPSV), 1.0f); s2 += v[c]; }
  float r2 = 1.f / s2;
  float* dp = P + (size_t)t * QS;
  float* dl = LOGU + (size_t)t * QS;
  #pragma unroll
  for (int c = 0; c < NCH; ++c) { float p = v[c] * r2; dp[c] = p; dl[c] = logf(p); }
}

// K4: Gaussian-kernel row sums (batch independent): rsg[i] = 1/sqrt(sum_j exp(-8*d2))
__global__ void k_rsg(float* __restrict__ rsg) {
  int i = blockIdx.x;
  int lane = threadIdx.x;
  int xi = i % HH, yi = i / HH;
  float s = 0.f;
  for (int j = lane; j < NP; j += 64) {
    if (j == i) continue;
    int xj = j % HH, yj = j / HH;
    float dx = (float)(xi - xj), dy = (float)(yi - yj);
    s += expf(-8.0f * (dx * dx + dy * dy));
  }
  s = wave_sum(s);
  if (lane == 0) rsg[i] = 1.f / sqrtf(s);
}

// K5: bilateral-kernel row sums per batch: rsb[n*NP+i]
__global__ void k_rsb(const float* __restrict__ colors, float* __restrict__ rsb) {
  int b = blockIdx.x;       // [0, NPIX)
  int nb = b / NP, i = b % NP;
  int lane = threadIdx.x;
  const float* ci = colors + (size_t)b * 4;
  float c0 = ci[0], c1 = ci[1], c2 = ci[2];
  int xi = i % HH, yi = i / HH;
  float s = 0.f;
  for (int j = lane; j < NP; j += 64) {
    if (j == i) continue;
    const float* cj = colors + ((size_t)nb * NP + j) * 4;
    float e0 = c0 - cj[0], e1 = c1 - cj[1], e2 = c2 - cj[2];
    float cd2 = e0 * e0 + e1 * e1 + e2 * e2;
    int xj = j % HH, yj = j / HH;
    float dx = (float)(xi - xj), dy = (float)(yi - yj);
    float d2 = dx * dx + dy * dy;
    s += expf(-0.01125f * d2 - cd2 * (1.0f / 338.0f));
  }
  s = wave_sum(s);
  if (lane == 0) rsb[b] = 1.f / sqrtf(s);
}

// K6: combined normalized kernel M[n][i][j] = 3*Kg_n + 10*Kb_n (symmetric, diag 0)
__global__ void k_buildM(const float* __restrict__ colors, const float* __restrict__ rsg,
                         const float* __restrict__ rsb, float* __restrict__ M) {
  int row = blockIdx.x;     // [0, NPIX)
  int nb = row / NP, i = row % NP;
  const float* ci = colors + (size_t)row * 4;
  float c0 = ci[0], c1 = ci[1], c2 = ci[2];
  float rg_i = rsg[i], rb_i = rsb[row];
  int xi = i % HH, yi = i / HH;
  float* Mrow = M + (size_t)row * NP;
  for (int j = threadIdx.x; j < NP; j += blockDim.x) {
    float val = 0.f;
    if (j != i) {
      const float* cj = colors + ((size_t)nb * NP + j) * 4;
      float e0 = c0 - cj[0], e1 = c1 - cj[1], e2 = c2 - cj[2];
      float cd2 = e0 * e0 + e1 * e1 + e2 * e2;
      int xj = j % HH, yj = j / HH;
      float dx = (float)(xi - xj), dy = (float)(yi - yj);
      float d2 = dx * dx + dy * dy;
      float kg = expf(-8.0f * d2) * rg_i * rsg[j];
      float kb = expf(-0.01125f * d2 - cd2 * (1.0f / 338.0f)) * rb_i * rsb[nb * NP + j];
      val = 3.0f * kg + 10.0f * kb;
    }
    Mrow[j] = val;
  }
}

// K7: one mean-field iteration: Qout = softmax_c(LOGU + M @ Qin)
// Block: 512 threads = 8 waves; block owns 64 i's (lane=i), waves split j (stride 8).
// Q chunk (256 rows, stride 24) staged in LDS; M read by symmetry as M[row j][col i]
// (coalesced across lanes).
__global__ __launch_bounds__(512) void k_iter(const float* __restrict__ M,
                                              const float* __restrict__ Qin,
                                              const float* __restrict__ LOGU,
                                              float* __restrict__ Qout) {
  __shared__ float Qs[512 * 24];   // 48 KB; staging uses first 256 rows, reduce uses all
  const int nb = blockIdx.x / ITILES;
  const int i0 = (blockIdx.x % ITILES) * 64;
  const int tid = (int)threadIdx.x;
  const int lane = tid & 63;
  const int wv = tid >> 6;         // 0..7
  const int i = i0 + lane;
  const bool valid = i < NP;
  const int im = valid ? i : NP - 1;

  float acc[NCH];
  #pragma unroll
  for (int c = 0; c < NCH; ++c) acc[c] = 0.f;

  const float* Qb = Qin + (size_t)nb * NP * QS;
  const float* Mb = M + (size_t)nb * NP * NP;

  for (int j0 = 0; j0 < NP; j0 += 256) {
    const int jmax = min(256, NP - j0);
    __syncthreads();
    {
      const int row = tid >> 1, half = tid & 1;
      if (row < jmax) {
        const float4* src = (const float4*)(Qb + (size_t)(j0 + row) * QS + half * 12);
        float4* dst = (float4*)(&Qs[row * 24 + half * 12]);
        dst[0] = src[0]; dst[1] = src[1]; dst[2] = src[2];
      }
    }
    __syncthreads();
    const float* mp = Mb + (size_t)(j0 + wv) * NP + im;
    #pragma unroll 2
    for (int jl = wv; jl < jmax; jl += 8) {
      const float m = *mp;
      mp += (size_t)8 * NP;
      const float4* qp = (const float4*)(&Qs[jl * 24]);
      float4 q0 = qp[0], q1 = qp[1], q2 = qp[2], q3 = qp[3], q4 = qp[4];
      float q20 = Qs[jl * 24 + 20];
      acc[0]  += m * q0.x; acc[1]  += m * q0.y; acc[2]  += m * q0.z; acc[3]  += m * q0.w;
      acc[4]  += m * q1.x; acc[5]  += m * q1.y; acc[6]  += m * q1.z; acc[7]  += m * q1.w;
      acc[8]  += m * q2.x; acc[9]  += m * q2.y; acc[10] += m * q2.z; acc[11] += m * q2.w;
      acc[12] += m * q3.x; acc[13] += m * q3.y; acc[14] += m * q3.z; acc[15] += m * q3.w;
      acc[16] += m * q4.x; acc[17] += m * q4.y; acc[18] += m * q4.z; acc[19] += m * q4.w;
      acc[20] += m * q20;
    }
  }

  // cross-wave reduction of the 8 partial message vectors per i
  __syncthreads();
  {
    float* mine = &Qs[tid * 24];
    #pragma unroll
    for (int c = 0; c < NCH; ++c) mine[c] = acc[c];
  }
  __syncthreads();
  if (wv == 0 && valid) {
    const float* lg = LOGU + ((size_t)nb * NP + i) * QS;
    float sv[NCH];
    float mx = -1e30f;
    #pragma unroll
    for (int c = 0; c < NCH; ++c) {
      float t = 0.f;
      #pragma unroll
      for (int w8 = 0; w8 < 8; ++w8) t += Qs[(w8 * 64 + lane) * 24 + c];
      t += lg[c];
      sv[c] = t;
      mx = fmaxf(mx, t);
    }
    float ssum = 0.f;
    #pragma unroll
    for (int c = 0; c < NCH; ++c) { sv[c] = expf(sv[c] - mx); ssum += sv[c]; }
    const float r = 1.f / ssum;
    float* dq = Qout + ((size_t)nb * NP + i) * QS;
    #pragma unroll
    for (int c = 0; c < NCH; ++c) dq[c] = sv[c] * r;
  }
}

// K8: per-pixel loss contribution, block-reduced partials
__global__ void k_loss(const float* __restrict__ Qf, const float* __restrict__ P,
                       float* __restrict__ part) {
  int t = blockIdx.x * blockDim.x + threadIdx.x;
  float s = 0.f;
  if (t < NPIX) {
    const float* q = Qf + (size_t)t * QS;
    const float* p = P + (size_t)t * QS;
    float qv[NCH];
    float qsum = 0.f;
    #pragma unroll
    for (int c = 0; c < NCH; ++c) { qv[c] = fmaxf(q[c], EPSV); qsum += qv[c]; }
    float r = 1.f / qsum;
    #pragma unroll
    for (int c = 0; c < NCH; ++c) {
      float qs = qv[c] * r;
      float ratio = fminf(fmaxf(qs / p[c], 0.05f), 20.0f);
      s += qs * logf(ratio);
    }
  }
  __shared__ float red[256];
  red[threadIdx.x] = s;
  __syncthreads();
  for (int st = 128; st > 0; st >>= 1) {
    if ((int)threadIdx.x < st) red[threadIdx.x] += red[threadIdx.x + st];
    __syncthreads();
  }
  if (threadIdx.x == 0) part[blockIdx.x] = red[0];
}

// K9: final reduction -> d_out[0]
__global__ void k_final(const float* __restrict__ part, float* __restrict__ out) {
  float s = 0.f;
  for (int k = threadIdx.x; k < LOSS_BLOCKS; k += 64) s += part[k];
  s = wave_sum(s);
  if (threadIdx.x == 0) out[0] = s / (float)NPIX;
}

}  // namespace

extern "C" void kernel_launch(void* const* d_in, const int* in_sizes, int n_in,
                              void* d_out, int out_size, void* d_ws, size_t ws_size,
                              hipStream_t stream) {
  const float* images  = (const float*)d_in[0];   // (16,3,321,321) fp32
  const float* predict = (const float*)d_in[1];   // (16,21,41,41) fp32
  float* out = (float*)d_out;
  float* ws = (float*)d_ws;

  float* W    = ws + OFF_W;
  float* COL  = ws + OFF_COL;
  float* P    = ws + OFF_P;
  float* LOGU = ws + OFF_LOGU;
  float* QA   = ws + OFF_QA;
  float* QB   = ws + OFF_QB;
  float* RSG  = ws + OFF_RSG;
  float* RSB  = ws + OFF_RSB;
  float* PART = ws + OFF_PART;
  float* M    = ws + OFF_M;

  hipLaunchKernelGGL(k_weights, dim3(1), dim3(64), 0, stream, W);
  hipLaunchKernelGGL(k_resize, dim3(LOSS_BLOCKS), dim3(256), 0, stream, images, W, COL);
  hipLaunchKernelGGL(k_probs, dim3(LOSS_BLOCKS), dim3(256), 0, stream, predict, P, LOGU);
  hipLaunchKernelGGL(k_rsg, dim3(NP), dim3(64), 0, stream, RSG);
  hipLaunchKernelGGL(k_rsb, dim3(NPIX), dim3(64), 0, stream, COL, RSB);
  hipLaunchKernelGGL(k_buildM, dim3(NPIX), dim3(256), 0, stream, COL, RSG, RSB, M);

  const float* qin = P;
  float* qout = QA;
  for (int it = 0; it < 10; ++it) {
    hipLaunchKernelGGL(k_iter, dim3(NBATCH * ITILES), dim3(512), 0, stream, M, qin, LOGU, qout);
    qin = qout;
    qout = (qout == QA) ? QB : QA;
  }
  // after 10 iterations, result is in QB (qin points at it)
  hipLaunchKernelGGL(k_loss, dim3(LOSS_BLOCKS), dim3(256), 0, stream, qin, P, PART);
  hipLaunchKernelGGL(k_final, dim3(1), dim3(64), 0, stream, PART, out);
}

// Round 2
// 762.253 us; speedup vs baseline: 1.1366x; 1.1366x over previous
//
#include <hip/hip_runtime.h>
#include <math.h>

namespace {

typedef unsigned short ushort_t;
typedef unsigned int uint_t;

constexpr int NBATCH = 16;
constexpr int NCH    = 21;
constexpr int HH     = 41;
constexpr int NP     = HH * HH;       // 1681 pixels
constexpr int IW     = 321;           // input image H=W
constexpr int QS     = 32;            // padded channel stride for P/LOGU/Q
constexpr float EPSV = 1e-5f;

constexpr int ITILES = (NP + 63) / 64;          // 27
constexpr int NPIX   = NBATCH * NP;             // 26896
constexpr int LOSS_BLOCKS = (NPIX + 255) / 256; // 106

// workspace offsets in floats (each 64-float aligned)
constexpr size_t OFF_W    = 0;                  // 41*321 = 13161
constexpr size_t OFF_COL  = 13184;              // colors [16][1681][4]
constexpr size_t OFF_P    = OFF_COL + 107584;   // probs  [16][1681][32]
constexpr size_t OFF_LOGU = OFF_P   + 860672;   // log(probs)
constexpr size_t OFF_QA   = OFF_LOGU + 860672;  // Q ping
constexpr size_t OFF_QB   = OFF_QA  + 860672;   // Q pong
constexpr size_t OFF_RSG  = OFF_QB  + 860672;   // 1/sqrt(sg) [1681]
constexpr size_t OFF_RSB  = OFF_RSG + 1728;     // 1/sqrt(sb) [16*1681]
constexpr size_t OFF_PART = OFF_RSB + 27008;    // loss partials
constexpr size_t OFF_M    = OFF_PART + 256;     // M bf16 [16][1681][1681] = 45,212,176 ushort
// total ~105 MB

__device__ __forceinline__ float wave_sum(float v) {
  #pragma unroll
  for (int off = 32; off > 0; off >>= 1) v += __shfl_down(v, off, 64);
  return v;
}

__device__ __forceinline__ ushort_t f32_to_bf16(float f) {
  union { float f; uint_t u; } v; v.f = f;
  uint_t r = (v.u + 0x7fffu + ((v.u >> 16) & 1u)) >> 16;   // RTN-even
  return (ushort_t)r;
}

__device__ __forceinline__ float bf16_to_f32(ushort_t u) {
  union { uint_t u; float f; } v; v.u = ((uint_t)u) << 16;
  return v.f;
}

// K1: jax.image.resize 'linear' (antialias=True) weight matrix, 321 -> 41.
__global__ void k_weights(float* __restrict__ W) {
  int o = threadIdx.x;
  if (o >= HH) return;
  const float inv = (float)IW / (float)HH;
  float s = (o + 0.5f) * inv - 0.5f;
  float tot = 0.f;
  for (int i = 0; i < IW; ++i) {
    float x = fabsf(s - (float)i) / inv;
    tot += fmaxf(0.f, 1.f - x);
  }
  float r = 1.f / tot;
  for (int i = 0; i < IW; ++i) {
    float x = fabsf(s - (float)i) / inv;
    W[o * IW + i] = fmaxf(0.f, 1.f - x) * r;
  }
}

// K2: filtered resize of images (16,3,321,321) -> colors [n][p][4] at 41x41
__global__ void k_resize(const float* __restrict__ img, const float* __restrict__ W,
                         float* __restrict__ colors) {
  int t = blockIdx.x * blockDim.x + threadIdx.x;
  if (t >= NPIX) return;
  int nb = t / NP, p = t % NP;
  int yo = p / HH, xo = p % HH;
  const float inv = (float)IW / (float)HH;
  float sy = (yo + 0.5f) * inv - 0.5f;
  float sx = (xo + 0.5f) * inv - 0.5f;
  int ylo = max(0, (int)ceilf(sy - inv)), yhi = min(IW - 1, (int)floorf(sy + inv));
  int xlo = max(0, (int)ceilf(sx - inv)), xhi = min(IW - 1, (int)floorf(sx + inv));
  float a0 = 0.f, a1 = 0.f, a2 = 0.f;
  for (int iy = ylo; iy <= yhi; ++iy) {
    float wy = W[yo * IW + iy];
    const float* base = img + ((size_t)nb * 3 * IW + iy) * IW;
    float r0 = 0.f, r1 = 0.f, r2 = 0.f;
    for (int ix = xlo; ix <= xhi; ++ix) {
      float wx = W[xo * IW + ix];
      r0 += wx * base[ix];
      r1 += wx * base[(size_t)IW * IW + ix];
      r2 += wx * base[2 * (size_t)IW * IW + ix];
    }
    a0 += wy * r0; a1 += wy * r1; a2 += wy * r2;
  }
  float* c = colors + (size_t)t * 4;
  c[0] = a0; c[1] = a1; c[2] = a2; c[3] = 0.f;
}

// K3: clamped channel softmax of predict -> P, LOGU (padded [n][i][32])
__global__ void k_probs(const float* __restrict__ pred, float* __restrict__ P,
                        float* __restrict__ LOGU) {
  int t = blockIdx.x * blockDim.x + threadIdx.x;
  if (t >= NPIX) return;
  int nb = t / NP, i = t % NP;
  const float* src = pred + (size_t)nb * NCH * NP + i;
  float v[NCH];
  float m = -1e30f;
  #pragma unroll
  for (int c = 0; c < NCH; ++c) { v[c] = src[(size_t)c * NP]; m = fmaxf(m, v[c]); }
  float s = 0.f;
  #pragma unroll
  for (int c = 0; c < NCH; ++c) { v[c] = expf(v[c] - m); s += v[c]; }
  float r = 1.f / s;
  float s2 = 0.f;
  #pragma unroll
  for (int c = 0; c < NCH; ++c) { v[c] = fminf(fmaxf(v[c] * r, EPSV), 1.0f); s2 += v[c]; }
  float r2 = 1.f / s2;
  float* dp = P + (size_t)t * QS;
  float* dl = LOGU + (size_t)t * QS;
  #pragma unroll
  for (int c = 0; c < NCH; ++c) { float p = v[c] * r2; dp[c] = p; dl[c] = logf(p); }
}

// K4: Gaussian-kernel row sums: rsg[i] = 1/sqrt(sum_{j!=i} exp(-8*d2))
__global__ void k_rsg(float* __restrict__ rsg) {
  int i = blockIdx.x;
  int lane = threadIdx.x;
  int xi = i % HH, yi = i / HH;
  float s = 0.f;
  for (int j = lane; j < NP; j += 64) {
    if (j == i) continue;
    int xj = j % HH, yj = j / HH;
    float dx = (float)(xi - xj), dy = (float)(yi - yj);
    s += __expf(-8.0f * (dx * dx + dy * dy));
  }
  s = wave_sum(s);
  if (lane == 0) rsg[i] = 1.f / sqrtf(s);
}

// K5: bilateral-kernel row sums per batch: rsb[n*NP+i]
__global__ void k_rsb(const float* __restrict__ colors, float* __restrict__ rsb) {
  int b = blockIdx.x;       // [0, NPIX)
  int nb = b / NP, i = b % NP;
  int lane = threadIdx.x;
  const float* ci = colors + (size_t)b * 4;
  float c0 = ci[0], c1 = ci[1], c2 = ci[2];
  int xi = i % HH, yi = i / HH;
  float s = 0.f;
  for (int j = lane; j < NP; j += 64) {
    if (j == i) continue;
    const float* cj = colors + ((size_t)nb * NP + j) * 4;
    float e0 = c0 - cj[0], e1 = c1 - cj[1], e2 = c2 - cj[2];
    float cd2 = e0 * e0 + e1 * e1 + e2 * e2;
    int xj = j % HH, yj = j / HH;
    float dx = (float)(xi - xj), dy = (float)(yi - yj);
    float d2 = dx * dx + dy * dy;
    s += __expf(-0.01125f * d2 - cd2 * (1.0f / 338.0f));
  }
  s = wave_sum(s);
  if (lane == 0) rsb[b] = 1.f / sqrtf(s);
}

// K6: combined normalized kernel M[n][i][j] = 3*Kg_n + 10*Kb_n (bf16, symmetric, diag 0)
__global__ void k_buildM(const float* __restrict__ colors, const float* __restrict__ rsg,
                         const float* __restrict__ rsb, ushort_t* __restrict__ M) {
  int row = blockIdx.x;     // [0, NPIX)
  int nb = row / NP, i = row % NP;
  const float* ci = colors + (size_t)row * 4;
  float c0 = ci[0], c1 = ci[1], c2 = ci[2];
  float rg_i = rsg[i], rb_i = rsb[row];
  int xi = i % HH, yi = i / HH;
  ushort_t* Mrow = M + (size_t)row * NP;
  for (int j = threadIdx.x; j < NP; j += blockDim.x) {
    float val = 0.f;
    if (j != i) {
      const float* cj = colors + ((size_t)nb * NP + j) * 4;
      float e0 = c0 - cj[0], e1 = c1 - cj[1], e2 = c2 - cj[2];
      float cd2 = e0 * e0 + e1 * e1 + e2 * e2;
      int xj = j % HH, yj = j / HH;
      float dx = (float)(xi - xj), dy = (float)(yi - yj);
      float d2 = dx * dx + dy * dy;
      float kg = __expf(-8.0f * d2) * rg_i * rsg[j];
      float kb = __expf(-0.01125f * d2 - cd2 * (1.0f / 338.0f)) * rb_i * rsb[nb * NP + j];
      val = 3.0f * kg + 10.0f * kb;
    }
    Mrow[j] = f32_to_bf16(val);
  }
}

// K7: one mean-field iteration: Qout = softmax_c(LOGU + M @ Qin)
// Block: 512 threads = 8 waves; block owns 64 i's (lane=i), waves split j (stride 8).
// Q[j] loaded through the SCALAR pipe (jl is wave-uniform -> s_load into SGPRs),
// M (bf16) loaded per-lane coalesced. No LDS in the hot loop.
__global__ __launch_bounds__(512) void k_iter(const ushort_t* __restrict__ M,
                                              const float* __restrict__ Qin,
                                              const float* __restrict__ LOGU,
                                              float* __restrict__ Qout) {
  __shared__ float Red[512 * 25];   // 50 KB, epilogue cross-wave reduce only
  const int nb = blockIdx.x / ITILES;
  const int i0 = (blockIdx.x % ITILES) * 64;
  const int tid = (int)threadIdx.x;
  const int lane = tid & 63;
  const int wv = __builtin_amdgcn_readfirstlane(tid >> 6);   // wave-uniform 0..7
  const int i = i0 + lane;
  const bool valid = i < NP;
  const int im = valid ? i : NP - 1;

  float acc[NCH];
  #pragma unroll
  for (int c = 0; c < NCH; ++c) acc[c] = 0.f;

  const float* Qb = Qin + (size_t)nb * NP * QS;
  const ushort_t* mp = M + (size_t)nb * NP * NP + (size_t)wv * NP + im;

  #pragma unroll 2
  for (int jl = wv; jl < NP; jl += 8) {
    const float mf = bf16_to_f32(*mp);
    mp += (size_t)8 * NP;
    const float* q = Qb + (size_t)jl * QS;    // wave-uniform address -> s_load
    #pragma unroll
    for (int c = 0; c < NCH; ++c) acc[c] = fmaf(mf, q[c], acc[c]);
  }

  // cross-wave reduction of the 8 partial message vectors per i (stride 25: conflict-free)
  {
    float* mine = &Red[tid * 25];
    #pragma unroll
    for (int c = 0; c < NCH; ++c) mine[c] = acc[c];
  }
  __syncthreads();
  if (wv == 0 && valid) {
    const float* lg = LOGU + ((size_t)nb * NP + i) * QS;
    float sv[NCH];
    float mx = -1e30f;
    #pragma unroll
    for (int c = 0; c < NCH; ++c) {
      float t = 0.f;
      #pragma unroll
      for (int w8 = 0; w8 < 8; ++w8) t += Red[(w8 * 64 + lane) * 25 + c];
      t += lg[c];
      sv[c] = t;
      mx = fmaxf(mx, t);
    }
    float ssum = 0.f;
    #pragma unroll
    for (int c = 0; c < NCH; ++c) { sv[c] = expf(sv[c] - mx); ssum += sv[c]; }
    const float r = 1.f / ssum;
    float* dq = Qout + ((size_t)nb * NP + i) * QS;
    #pragma unroll
    for (int c = 0; c < NCH; ++c) dq[c] = sv[c] * r;
  }
}

// K8: per-pixel loss contribution, block-reduced partials
__global__ void k_loss(const float* __restrict__ Qf, const float* __restrict__ P,
                       float* __restrict__ part) {
  int t = blockIdx.x * blockDim.x + threadIdx.x;
  float s = 0.f;
  if (t < NPIX) {
    const float* q = Qf + (size_t)t * QS;
    const float* p = P + (size_t)t * QS;
    float qv[NCH];
    float qsum = 0.f;
    #pragma unroll
    for (int c = 0; c < NCH; ++c) { qv[c] = fmaxf(q[c], EPSV); qsum += qv[c]; }
    float r = 1.f / qsum;
    #pragma unroll
    for (int c = 0; c < NCH; ++c) {
      float qs = qv[c] * r;
      float ratio = fminf(fmaxf(qs / p[c], 0.05f), 20.0f);
      s += qs * logf(ratio);
    }
  }
  __shared__ float red[256];
  red[threadIdx.x] = s;
  __syncthreads();
  for (int st = 128; st > 0; st >>= 1) {
    if ((int)threadIdx.x < st) red[threadIdx.x] += red[threadIdx.x + st];
    __syncthreads();
  }
  if (threadIdx.x == 0) part[blockIdx.x] = red[0];
}

// K9: final reduction -> d_out[0]
__global__ void k_final(const float* __restrict__ part, float* __restrict__ out) {
  float s = 0.f;
  for (int k = threadIdx.x; k < LOSS_BLOCKS; k += 64) s += part[k];
  s = wave_sum(s);
  if (threadIdx.x == 0) out[0] = s / (float)NPIX;
}

}  // namespace

extern "C" void kernel_launch(void* const* d_in, const int* in_sizes, int n_in,
                              void* d_out, int out_size, void* d_ws, size_t ws_size,
                              hipStream_t stream) {
  const float* images  = (const float*)d_in[0];   // (16,3,321,321) fp32
  const float* predict = (const float*)d_in[1];   // (16,21,41,41) fp32
  float* out = (float*)d_out;
  float* ws = (float*)d_ws;

  float* W    = ws + OFF_W;
  float* COL  = ws + OFF_COL;
  float* P    = ws + OFF_P;
  float* LOGU = ws + OFF_LOGU;
  float* QA   = ws + OFF_QA;
  float* QB   = ws + OFF_QB;
  float* RSG  = ws + OFF_RSG;
  float* RSB  = ws + OFF_RSB;
  float* PART = ws + OFF_PART;
  ushort_t* M = (ushort_t*)(ws + OFF_M);

  hipLaunchKernelGGL(k_weights, dim3(1), dim3(64), 0, stream, W);
  hipLaunchKernelGGL(k_resize, dim3(LOSS_BLOCKS), dim3(256), 0, stream, images, W, COL);
  hipLaunchKernelGGL(k_probs, dim3(LOSS_BLOCKS), dim3(256), 0, stream, predict, P, LOGU);
  hipLaunchKernelGGL(k_rsg, dim3(NP), dim3(64), 0, stream, RSG);
  hipLaunchKernelGGL(k_rsb, dim3(NPIX), dim3(64), 0, stream, COL, RSB);
  hipLaunchKernelGGL(k_buildM, dim3(NPIX), dim3(256), 0, stream, COL, RSG, RSB, M);

  const float* qin = P;
  float* qout = QA;
  for (int it = 0; it < 10; ++it) {
    hipLaunchKernelGGL(k_iter, dim3(NBATCH * ITILES), dim3(512), 0, stream, M, qin, LOGU, qout);
    qin = qout;
    qout = (qout == QA) ? QB : QA;
  }
  hipLaunchKernelGGL(k_loss, dim3(LOSS_BLOCKS), dim3(256), 0, stream, qin, P, PART);
  hipLaunchKernelGGL(k_final, dim3(1), dim3(64), 0, stream, PART, out);
}

// Round 3
// 572.677 us; speedup vs baseline: 1.5129x; 1.3310x over previous
//
#include <hip/hip_runtime.h>
#include <math.h>

namespace {

typedef unsigned short ushort_t;
typedef unsigned int uint_t;
typedef __attribute__((ext_vector_type(8))) short short8;
typedef __attribute__((ext_vector_type(4))) float f32x4;

constexpr int NBATCH = 16;
constexpr int NCH    = 21;
constexpr int HH     = 41;
constexpr int NP     = HH * HH;       // 1681 pixels
constexpr int IW     = 321;           // input image H=W
constexpr int QS     = 32;            // padded channel stride for P/LOGU/QF
constexpr float EPSV = 1e-5f;

constexpr int NPAD   = 1696;          // NP padded to 53*32 (K and row tiles)
constexpr int NKB    = 53;            // K blocks of 32
constexpr int NIT    = 106;           // i-tiles of 16 (1696/16)
constexpr int NPIX   = NBATCH * NP;             // 26896
constexpr int LOSS_BLOCKS = (NPIX + 255) / 256; // 106

// B-fragment-linear Q storage: per batch [53 kb][2 ct][64 lane][8 j] bf16
constexpr int QB_BATCH = NKB * 2 * 512;          // 54272 ushorts per batch
constexpr int QB_HALF  = NBATCH * QB_BATCH;      // 868352 ushorts (hi or lo)
constexpr int RXN = NBATCH * 3 * IW * HH;        // 631728

// workspace offsets in floats
constexpr size_t OFF_W    = 0;                   // 13161 -> 13184
constexpr size_t OFF_RX   = 13184;               // 631728 -> 631744
constexpr size_t OFF_COL  = 644928;              // colors [16][1681][4] -> 107584
constexpr size_t OFF_P    = 752512;              // probs [npix][32]
constexpr size_t OFF_LOGU = 1613184;
constexpr size_t OFF_QF   = 2473856;             // fp32 Q (written each iter)
constexpr size_t OFF_RSG  = 3334528;             // 1728
constexpr size_t OFF_RSB  = 3336256;             // 27008
constexpr size_t OFF_PART = 3363264;             // 256
constexpr size_t OFF_QB   = 3363520;             // 4*868352 ushorts = 1736704 floats
constexpr size_t OFF_M    = 5100224;             // bf16 M [16][1696][1696] = 23,011,328 floats
// total = 28,111,552 floats = 112.4 MB (ws proven >= 195 MB in round 1)

constexpr size_t QB_DWORDS = (size_t)QB_HALF * 4 / 2;  // 4 halves total, in dwords = 1,736,704

__device__ __forceinline__ float wave_sum(float v) {
  #pragma unroll
  for (int off = 32; off > 0; off >>= 1) v += __shfl_down(v, off, 64);
  return v;
}

__device__ __forceinline__ ushort_t f32_to_bf16(float f) {
  union { float f; uint_t u; } v; v.f = f;
  uint_t r = (v.u + 0x7fffu + ((v.u >> 16) & 1u)) >> 16;   // RTN-even
  return (ushort_t)r;
}

__device__ __forceinline__ float bf16_to_f32(ushort_t u) {
  union { uint_t u; float f; } v; v.u = ((uint_t)u) << 16;
  return v.f;
}

// zero the QB region (pads must be exactly 0 for MFMA K/row padding)
__global__ void k_zero(uint_t* __restrict__ p) {
  size_t t = (size_t)blockIdx.x * blockDim.x + threadIdx.x;
  if (t < QB_DWORDS) p[t] = 0u;
}

// K1: jax.image.resize 'linear' (antialias=True) weight matrix, 321 -> 41.
__global__ void k_weights(float* __restrict__ W) {
  int o = threadIdx.x;
  if (o >= HH) return;
  const float inv = (float)IW / (float)HH;
  float s = (o + 0.5f) * inv - 0.5f;
  float tot = 0.f;
  for (int i = 0; i < IW; ++i) {
    float x = fabsf(s - (float)i) / inv;
    tot += fmaxf(0.f, 1.f - x);
  }
  float r = 1.f / tot;
  for (int i = 0; i < IW; ++i) {
    float x = fabsf(s - (float)i) / inv;
    W[o * IW + i] = fmaxf(0.f, 1.f - x) * r;
  }
}

// K2a: separable resize, x pass: RX[n][ch][y][xo] = sum_ix W[xo][ix]*img[n][ch][y][ix]
__global__ void k_resize_x(const float* __restrict__ img, const float* __restrict__ W,
                           float* __restrict__ RX) {
  int t = blockIdx.x * blockDim.x + threadIdx.x;
  if (t >= RXN) return;
  int xo = t % HH;
  int rest = t / HH;
  int y = rest % IW;
  int nc = rest / IW;                 // nb*3 + ch
  const float inv = (float)IW / (float)HH;
  float sx = (xo + 0.5f) * inv - 0.5f;
  int xlo = max(0, (int)ceilf(sx - inv)), xhi = min(IW - 1, (int)floorf(sx + inv));
  const float* base = img + ((size_t)nc * IW + y) * IW;
  const float* wr = W + xo * IW;
  float a = 0.f;
  for (int ix = xlo; ix <= xhi; ++ix) a += wr[ix] * base[ix];
  RX[t] = a;
}

// K2b: y pass -> colors [n][p][4]
__global__ void k_resize_y(const float* __restrict__ RX, const float* __restrict__ W,
                           float* __restrict__ colors) {
  int t = blockIdx.x * blockDim.x + threadIdx.x;
  if (t >= NPIX) return;
  int nb = t / NP, p = t % NP;
  int yo = p / HH, xo = p % HH;
  const float inv = (float)IW / (float)HH;
  float sy = (yo + 0.5f) * inv - 0.5f;
  int ylo = max(0, (int)ceilf(sy - inv)), yhi = min(IW - 1, (int)floorf(sy + inv));
  const float* wr = W + yo * IW;
  float a0 = 0.f, a1 = 0.f, a2 = 0.f;
  const float* b0 = RX + (size_t)(nb * 3 + 0) * IW * HH + xo;
  const float* b1 = RX + (size_t)(nb * 3 + 1) * IW * HH + xo;
  const float* b2 = RX + (size_t)(nb * 3 + 2) * IW * HH + xo;
  for (int iy = ylo; iy <= yhi; ++iy) {
    float wy = wr[iy];
    a0 += wy * b0[(size_t)iy * HH];
    a1 += wy * b1[(size_t)iy * HH];
    a2 += wy * b2[(size_t)iy * HH];
  }
  float* c = colors + (size_t)t * 4;
  c[0] = a0; c[1] = a1; c[2] = a2; c[3] = 0.f;
}

// K3: clamped channel softmax -> P, LOGU, and initial swizzled bf16 hi/lo B-fragments
__global__ void k_probs(const float* __restrict__ pred, float* __restrict__ P,
                        float* __restrict__ LOGU, ushort_t* __restrict__ QB) {
  int t = blockIdx.x * blockDim.x + threadIdx.x;
  if (t >= NPIX) return;
  int nb = t / NP, i = t % NP;
  const float* src = pred + (size_t)nb * NCH * NP + i;
  float v[NCH];
  float m = -1e30f;
  #pragma unroll
  for (int c = 0; c < NCH; ++c) { v[c] = src[(size_t)c * NP]; m = fmaxf(m, v[c]); }
  float s = 0.f;
  #pragma unroll
  for (int c = 0; c < NCH; ++c) { v[c] = expf(v[c] - m); s += v[c]; }
  float r = 1.f / s;
  float s2 = 0.f;
  #pragma unroll
  for (int c = 0; c < NCH; ++c) { v[c] = fminf(fmaxf(v[c] * r, EPSV), 1.0f); s2 += v[c]; }
  float r2 = 1.f / s2;
  float* dp = P + (size_t)t * QS;
  float* dl = LOGU + (size_t)t * QS;
  int kb = i >> 5, kr = i & 31, q2 = kr >> 3, j = kr & 7;
  size_t sb = (size_t)nb * QB_BATCH + (size_t)kb * 1024 + j;
  #pragma unroll
  for (int c = 0; c < NCH; ++c) {
    float p = v[c] * r2;
    dp[c] = p; dl[c] = logf(p);
    int ct = c >> 4;
    size_t addr = sb + (size_t)ct * 512 + (q2 * 16 + (c & 15)) * 8;
    ushort_t h = f32_to_bf16(p);
    float lo = p - bf16_to_f32(h);
    QB[addr] = h;
    QB[addr + QB_HALF] = f32_to_bf16(lo);
  }
}

// K4: Gaussian-kernel row sums: rsg[i] = 1/sqrt(sum_{j!=i} exp(-8*d2))
__global__ void k_rsg(float* __restrict__ rsg) {
  int i = blockIdx.x;
  int lane = threadIdx.x;
  int xi = i % HH, yi = i / HH;
  float s = 0.f;
  for (int j = lane; j < NP; j += 64) {
    if (j == i) continue;
    int xj = j % HH, yj = j / HH;
    float dx = (float)(xi - xj), dy = (float)(yi - yj);
    s += __expf(-8.0f * (dx * dx + dy * dy));
  }
  s = wave_sum(s);
  if (lane == 0) rsg[i] = 1.f / sqrtf(s);
}

// K5: bilateral-kernel row sums per batch: rsb[n*NP+i]
__global__ void k_rsb(const float* __restrict__ colors, float* __restrict__ rsb) {
  int b = blockIdx.x;
  int nb = b / NP, i = b % NP;
  int lane = threadIdx.x;
  const float* ci = colors + (size_t)b * 4;
  float c0 = ci[0], c1 = ci[1], c2 = ci[2];
  int xi = i % HH, yi = i / HH;
  float s = 0.f;
  for (int j = lane; j < NP; j += 64) {
    if (j == i) continue;
    const float* cj = colors + ((size_t)nb * NP + j) * 4;
    float e0 = c0 - cj[0], e1 = c1 - cj[1], e2 = c2 - cj[2];
    float cd2 = e0 * e0 + e1 * e1 + e2 * e2;
    int xj = j % HH, yj = j / HH;
    float dx = (float)(xi - xj), dy = (float)(yi - yj);
    float d2 = dx * dx + dy * dy;
    s += __expf(-0.01125f * d2 - cd2 * (1.0f / 338.0f));
  }
  s = wave_sum(s);
  if (lane == 0) rsb[b] = 1.f / sqrtf(s);
}

// K6: M[n][i][j] = 3*Kg_n + 10*Kb_n (bf16, diag 0), row stride NPAD, cols [NP,NPAD) zeroed
__global__ void k_buildM(const float* __restrict__ colors, const float* __restrict__ rsg,
                         const float* __restrict__ rsb, ushort_t* __restrict__ M) {
  int row = blockIdx.x;     // [0, NPIX)
  int nb = row / NP, i = row % NP;
  const float* ci = colors + (size_t)row * 4;
  float c0 = ci[0], c1 = ci[1], c2 = ci[2];
  float rg_i = rsg[i], rb_i = rsb[row];
  int xi = i % HH, yi = i / HH;
  ushort_t* Mrow = M + ((size_t)nb * NPAD + i) * NPAD;
  for (int j = threadIdx.x; j < NPAD; j += blockDim.x) {
    float val = 0.f;
    if (j < NP && j != i) {
      const float* cj = colors + ((size_t)nb * NP + j) * 4;
      float e0 = c0 - cj[0], e1 = c1 - cj[1], e2 = c2 - cj[2];
      float cd2 = e0 * e0 + e1 * e1 + e2 * e2;
      int xj = j % HH, yj = j / HH;
      float dx = (float)(xi - xj), dy = (float)(yi - yj);
      float d2 = dx * dx + dy * dy;
      float kg = __expf(-8.0f * d2) * rg_i * rsg[j];
      float kb = __expf(-0.01125f * d2 - cd2 * (1.0f / 338.0f)) * rb_i * rsb[nb * NP + j];
      val = 3.0f * kg + 10.0f * kb;
    }
    Mrow[j] = f32_to_bf16(val);
  }
}

// K7: one mean-field iteration via MFMA.
// Block = 1 wave, owns a 16-row i-tile. C(16x32) = M-tile(16x1696) x Q(1696x32),
// Q as bf16 hi+lo split in B-fragment-linear order. Epilogue: channel softmax via
// shfl_xor over 16-lane groups; writes fp32 QF + next iteration's B-fragments.
__global__ __launch_bounds__(64) void k_iter(const ushort_t* __restrict__ M,
                                             const ushort_t* __restrict__ QBin,
                                             ushort_t* __restrict__ QBout,
                                             const float* __restrict__ LOGU,
                                             float* __restrict__ QF) {
  const int nb = blockIdx.x / NIT;
  const int t0 = (blockIdx.x % NIT) * 16;
  const int lane = (int)threadIdx.x;
  const int mrow = lane & 15, quad = lane >> 4;

  f32x4 acc0 = {0.f, 0.f, 0.f, 0.f};
  f32x4 acc1 = {0.f, 0.f, 0.f, 0.f};

  const ushort_t* Ap = M + ((size_t)nb * NPAD + t0 + mrow) * NPAD + quad * 8;
  const ushort_t* Bh = QBin + (size_t)nb * QB_BATCH + lane * 8;
  const ushort_t* Bl = Bh + QB_HALF;

  #pragma unroll 2
  for (int kb = 0; kb < NKB; ++kb) {
    short8 a   = *(const short8*)(Ap);
    short8 bh0 = *(const short8*)(Bh);
    short8 bh1 = *(const short8*)(Bh + 512);
    short8 bl0 = *(const short8*)(Bl);
    short8 bl1 = *(const short8*)(Bl + 512);
    Ap += 32; Bh += 1024; Bl += 1024;
    acc0 = __builtin_amdgcn_mfma_f32_16x16x32_bf16(a, bh0, acc0, 0, 0, 0);
    acc0 = __builtin_amdgcn_mfma_f32_16x16x32_bf16(a, bl0, acc0, 0, 0, 0);
    acc1 = __builtin_amdgcn_mfma_f32_16x16x32_bf16(a, bh1, acc1, 0, 0, 0);
    acc1 = __builtin_amdgcn_mfma_f32_16x16x32_bf16(a, bl1, acc1, 0, 0, 0);
  }

  const bool c1ok = (mrow + 16) < NCH;    // ct1 col valid (16..20)
  #pragma unroll
  for (int reg = 0; reg < 4; ++reg) {
    int r = t0 + quad * 4 + reg;          // global row (i); rows >= NP masked at store
    int rg = nb * NP + min(r, NP - 1);
    float tv0 = LOGU[(size_t)rg * QS + mrow] + acc0[reg];
    float tv1 = c1ok ? (LOGU[(size_t)rg * QS + 16 + mrow] + acc1[reg]) : -1e30f;
    float mx = fmaxf(tv0, tv1);
    mx = fmaxf(mx, __shfl_xor(mx, 1));
    mx = fmaxf(mx, __shfl_xor(mx, 2));
    mx = fmaxf(mx, __shfl_xor(mx, 4));
    mx = fmaxf(mx, __shfl_xor(mx, 8));
    float e0 = __expf(tv0 - mx);
    float e1 = c1ok ? __expf(tv1 - mx) : 0.f;
    float sm = e0 + e1;
    sm += __shfl_xor(sm, 1);
    sm += __shfl_xor(sm, 2);
    sm += __shfl_xor(sm, 4);
    sm += __shfl_xor(sm, 8);
    float rinv = 1.f / sm;
    if (r < NP) {
      int kb = r >> 5, kr = r & 31, q2 = kr >> 3, j = kr & 7;
      size_t sb = (size_t)nb * QB_BATCH + (size_t)kb * 1024 + (q2 * 16 + mrow) * 8 + j;
      float q0 = e0 * rinv;
      QF[(size_t)(nb * NP + r) * QS + mrow] = q0;
      ushort_t h0 = f32_to_bf16(q0);
      QBout[sb] = h0;
      QBout[sb + QB_HALF] = f32_to_bf16(q0 - bf16_to_f32(h0));
      if (c1ok) {
        float q1 = e1 * rinv;
        QF[(size_t)(nb * NP + r) * QS + 16 + mrow] = q1;
        ushort_t h1 = f32_to_bf16(q1);
        QBout[sb + 512] = h1;
        QBout[sb + 512 + QB_HALF] = f32_to_bf16(q1 - bf16_to_f32(h1));
      }
    }
  }
}

// K8: per-pixel loss contribution, block-reduced partials
__global__ void k_loss(const float* __restrict__ Qf, const float* __restrict__ P,
                       float* __restrict__ part) {
  int t = blockIdx.x * blockDim.x + threadIdx.x;
  float s = 0.f;
  if (t < NPIX) {
    const float* q = Qf + (size_t)t * QS;
    const float* p = P + (size_t)t * QS;
    float qv[NCH];
    float qsum = 0.f;
    #pragma unroll
    for (int c = 0; c < NCH; ++c) { qv[c] = fmaxf(q[c], EPSV); qsum += qv[c]; }
    float r = 1.f / qsum;
    #pragma unroll
    for (int c = 0; c < NCH; ++c) {
      float qs = qv[c] * r;
      float ratio = fminf(fmaxf(qs / p[c], 0.05f), 20.0f);
      s += qs * logf(ratio);
    }
  }
  __shared__ float red[256];
  red[threadIdx.x] = s;
  __syncthreads();
  for (int st = 128; st > 0; st >>= 1) {
    if ((int)threadIdx.x < st) red[threadIdx.x] += red[threadIdx.x + st];
    __syncthreads();
  }
  if (threadIdx.x == 0) part[blockIdx.x] = red[0];
}

// K9: final reduction -> d_out[0]
__global__ void k_final(const float* __restrict__ part, float* __restrict__ out) {
  float s = 0.f;
  for (int k = threadIdx.x; k < LOSS_BLOCKS; k += 64) s += part[k];
  s = wave_sum(s);
  if (threadIdx.x == 0) out[0] = s / (float)NPIX;
}

}  // namespace

extern "C" void kernel_launch(void* const* d_in, const int* in_sizes, int n_in,
                              void* d_out, int out_size, void* d_ws, size_t ws_size,
                              hipStream_t stream) {
  const float* images  = (const float*)d_in[0];   // (16,3,321,321) fp32
  const float* predict = (const float*)d_in[1];   // (16,21,41,41) fp32
  float* out = (float*)d_out;
  float* ws = (float*)d_ws;

  float* W    = ws + OFF_W;
  float* RX   = ws + OFF_RX;
  float* COL  = ws + OFF_COL;
  float* P    = ws + OFF_P;
  float* LOGU = ws + OFF_LOGU;
  float* QF   = ws + OFF_QF;
  float* RSG  = ws + OFF_RSG;
  float* RSB  = ws + OFF_RSB;
  float* PART = ws + OFF_PART;
  ushort_t* QB_A = (ushort_t*)(ws + OFF_QB);
  ushort_t* QB_B = QB_A + 2 * (size_t)QB_HALF;
  ushort_t* M    = (ushort_t*)(ws + OFF_M);

  hipLaunchKernelGGL(k_zero, dim3((unsigned)((QB_DWORDS + 255) / 256)), dim3(256), 0, stream,
                     (uint_t*)QB_A);
  hipLaunchKernelGGL(k_weights, dim3(1), dim3(64), 0, stream, W);
  hipLaunchKernelGGL(k_resize_x, dim3((RXN + 255) / 256), dim3(256), 0, stream, images, W, RX);
  hipLaunchKernelGGL(k_resize_y, dim3(LOSS_BLOCKS), dim3(256), 0, stream, RX, W, COL);
  hipLaunchKernelGGL(k_probs, dim3(LOSS_BLOCKS), dim3(256), 0, stream, predict, P, LOGU, QB_A);
  hipLaunchKernelGGL(k_rsg, dim3(NP), dim3(64), 0, stream, RSG);
  hipLaunchKernelGGL(k_rsb, dim3(NPIX), dim3(64), 0, stream, COL, RSB);
  hipLaunchKernelGGL(k_buildM, dim3(NPIX), dim3(256), 0, stream, COL, RSG, RSB, M);

  const ushort_t* qbin = QB_A;
  ushort_t* qbout = QB_B;
  for (int it = 0; it < 10; ++it) {
    hipLaunchKernelGGL(k_iter, dim3(NBATCH * NIT), dim3(64), 0, stream, M, qbin, qbout, LOGU, QF);
    const ushort_t* t = qbout; qbout = (ushort_t*)qbin; qbin = t;
  }
  hipLaunchKernelGGL(k_loss, dim3(LOSS_BLOCKS), dim3(256), 0, stream, QF, P, PART);
  hipLaunchKernelGGL(k_final, dim3(1), dim3(64), 0, stream, PART, out);
}

// Round 4
// 476.494 us; speedup vs baseline: 1.8183x; 1.2019x over previous
//
#include <hip/hip_runtime.h>
#include <math.h>

namespace {

typedef unsigned short ushort_t;
typedef unsigned int uint_t;
typedef __attribute__((ext_vector_type(8))) short short8;
typedef __attribute__((ext_vector_type(4))) float f32x4;

constexpr int NBATCH = 16;
constexpr int NCH    = 21;
constexpr int HH     = 41;
constexpr int NP     = HH * HH;       // 1681 pixels
constexpr int IW     = 321;           // input image H=W
constexpr int QS     = 32;            // padded channel stride for P/LOGU/QF
constexpr float EPSV = 1e-5f;

constexpr int NPAD   = 1696;          // NP padded to 53*32
constexpr int NKB    = 53;            // K blocks of 32
constexpr int RPB    = 32;            // rows per k_iter block
constexpr int NBLK   = NPAD / RPB;    // 53 row-blocks per batch
constexpr int NPIX   = NBATCH * NP;             // 26896
constexpr int LOSS_BLOCKS = (NPIX + 255) / 256; // 106

// B-fragment-linear Q storage: per batch [53 kb][2 ct][64 lane][8 j] bf16
constexpr int QB_BATCH = NKB * 2 * 512;          // 54272 ushorts per batch
constexpr int QB_BUF   = NBATCH * QB_BATCH;      // 868352 ushorts per buffer
constexpr int RXN = NBATCH * 3 * IW * HH;        // 631728

// 5-D distance scaling: exp(-0.01125*d2 - cd2/338) == exp2(-(|scaled xy diff|^2+|scaled col diff|^2))
constexpr float CS_COLOR = 0.06533245f;   // sqrt(log2(e)/338)
constexpr float CS_XY    = 0.12739827f;   // sqrt(0.01125*log2(e))
constexpr float KGC      = 711.111111f;   // 8/0.01125 : exp(-8*d2)=exp2(-KGC*axy)
constexpr float L2E8     = 11.5415603f;   // 8*log2(e)
constexpr float GATE     = 0.138f;        // axy threshold ~ d2<=8 (dropped kg < 1e-25)

// workspace offsets in floats
constexpr size_t OFF_W    = 0;                   // 13184
constexpr size_t OFF_RX   = 13184;               // 631744
constexpr size_t OFF_COL  = 644928;              // scaled colors+rsb.w [npix][4]
constexpr size_t OFF_P    = 752512;              // 860672
constexpr size_t OFF_LOGU = 1613184;             // 860672
constexpr size_t OFF_QF   = 2473856;             // 860672
constexpr size_t OFF_RSG  = 3334528;             // 1728
constexpr size_t OFF_XY   = 3336256;             // 3456 (NPAD float2)
constexpr size_t OFF_PART = 3339712;             // 256
constexpr size_t OFF_QB   = 3339968;             // 2 buffers * 434176 floats
constexpr size_t OFF_M    = 4208320;             // bf16 M [16][1696][1696]
// total ~107.8 MB

constexpr size_t QB_ZERO_DWORDS = (size_t)QB_BUF;  // 2 buffers * QB_BUF/2 dwords each

__device__ __forceinline__ float wave_sum(float v) {
  #pragma unroll
  for (int off = 32; off > 0; off >>= 1) v += __shfl_down(v, off, 64);
  return v;
}

__device__ __forceinline__ ushort_t f32_to_bf16(float f) {
  union { float f; uint_t u; } v; v.f = f;
  uint_t r = (v.u + 0x7fffu + ((v.u >> 16) & 1u)) >> 16;   // RTN-even
  return (ushort_t)r;
}

__global__ void k_zero(uint_t* __restrict__ p) {
  size_t t = (size_t)blockIdx.x * blockDim.x + threadIdx.x;
  if (t < QB_ZERO_DWORDS) p[t] = 0u;
}

// K1: jax.image.resize 'linear' (antialias) weight matrix, 321 -> 41.
__global__ void k_weights(float* __restrict__ W) {
  int o = threadIdx.x;
  if (o >= HH) return;
  const float inv = (float)IW / (float)HH;
  float s = (o + 0.5f) * inv - 0.5f;
  float tot = 0.f;
  for (int i = 0; i < IW; ++i) {
    float x = fabsf(s - (float)i) / inv;
    tot += fmaxf(0.f, 1.f - x);
  }
  float r = 1.f / tot;
  for (int i = 0; i < IW; ++i) {
    float x = fabsf(s - (float)i) / inv;
    W[o * IW + i] = fmaxf(0.f, 1.f - x) * r;
  }
}

// scaled pixel-grid coordinate table (pads pushed far away so exp2 -> 0)
__global__ void k_xy(float2* __restrict__ XY) {
  int j = blockIdx.x * blockDim.x + threadIdx.x;
  if (j >= NPAD) return;
  if (j < NP) XY[j] = make_float2((float)(j % HH) * CS_XY, (float)(j / HH) * CS_XY);
  else        XY[j] = make_float2(1e4f, 1e4f);
}

// K2a: separable resize, x pass
__global__ void k_resize_x(const float* __restrict__ img, const float* __restrict__ W,
                           float* __restrict__ RX) {
  int t = blockIdx.x * blockDim.x + threadIdx.x;
  if (t >= RXN) return;
  int xo = t % HH;
  int rest = t / HH;
  int y = rest % IW;
  int nc = rest / IW;
  const float inv = (float)IW / (float)HH;
  float sx = (xo + 0.5f) * inv - 0.5f;
  int xlo = max(0, (int)ceilf(sx - inv)), xhi = min(IW - 1, (int)floorf(sx + inv));
  const float* base = img + ((size_t)nc * IW + y) * IW;
  const float* wr = W + xo * IW;
  float a = 0.f;
  for (int ix = xlo; ix <= xhi; ++ix) a += wr[ix] * base[ix];
  RX[t] = a;
}

// K2b: y pass -> SCALED colors [n][p][4] (w=0, later filled with rsb)
__global__ void k_resize_y(const float* __restrict__ RX, const float* __restrict__ W,
                           float* __restrict__ colors) {
  int t = blockIdx.x * blockDim.x + threadIdx.x;
  if (t >= NPIX) return;
  int nb = t / NP, p = t % NP;
  int yo = p / HH, xo = p % HH;
  const float inv = (float)IW / (float)HH;
  float sy = (yo + 0.5f) * inv - 0.5f;
  int ylo = max(0, (int)ceilf(sy - inv)), yhi = min(IW - 1, (int)floorf(sy + inv));
  const float* wr = W + yo * IW;
  float a0 = 0.f, a1 = 0.f, a2 = 0.f;
  const float* b0 = RX + (size_t)(nb * 3 + 0) * IW * HH + xo;
  const float* b1 = RX + (size_t)(nb * 3 + 1) * IW * HH + xo;
  const float* b2 = RX + (size_t)(nb * 3 + 2) * IW * HH + xo;
  for (int iy = ylo; iy <= yhi; ++iy) {
    float wy = wr[iy];
    a0 += wy * b0[(size_t)iy * HH];
    a1 += wy * b1[(size_t)iy * HH];
    a2 += wy * b2[(size_t)iy * HH];
  }
  float* c = colors + (size_t)t * 4;
  c[0] = a0 * CS_COLOR; c[1] = a1 * CS_COLOR; c[2] = a2 * CS_COLOR; c[3] = 0.f;
}

// K3: clamped channel softmax -> P, LOGU, initial bf16 B-fragments
__global__ void k_probs(const float* __restrict__ pred, float* __restrict__ P,
                        float* __restrict__ LOGU, ushort_t* __restrict__ QB) {
  int t = blockIdx.x * blockDim.x + threadIdx.x;
  if (t >= NPIX) return;
  int nb = t / NP, i = t % NP;
  const float* src = pred + (size_t)nb * NCH * NP + i;
  float v[NCH];
  float m = -1e30f;
  #pragma unroll
  for (int c = 0; c < NCH; ++c) { v[c] = src[(size_t)c * NP]; m = fmaxf(m, v[c]); }
  float s = 0.f;
  #pragma unroll
  for (int c = 0; c < NCH; ++c) { v[c] = expf(v[c] - m); s += v[c]; }
  float r = 1.f / s;
  float s2 = 0.f;
  #pragma unroll
  for (int c = 0; c < NCH; ++c) { v[c] = fminf(fmaxf(v[c] * r, EPSV), 1.0f); s2 += v[c]; }
  float r2 = 1.f / s2;
  float* dp = P + (size_t)t * QS;
  float* dl = LOGU + (size_t)t * QS;
  int kb = i >> 5, kr = i & 31, q2 = kr >> 3, j = kr & 7;
  size_t sb = (size_t)nb * QB_BATCH + (size_t)kb * 1024 + j;
  #pragma unroll
  for (int c = 0; c < NCH; ++c) {
    float p = v[c] * r2;
    dp[c] = p; dl[c] = logf(p);
    int ct = c >> 4;
    QB[sb + (size_t)ct * 512 + (q2 * 16 + (c & 15)) * 8] = f32_to_bf16(p);
  }
}

// K4: Gaussian row sums: rsg[i] = 1/sqrt(sum_{j!=i} exp(-8*d2))
__global__ void k_rsg(float* __restrict__ rsg) {
  int i = blockIdx.x;
  int lane = threadIdx.x;
  int xi = i % HH, yi = i / HH;
  float s = 0.f;
  for (int j = lane; j < NP; j += 64) {
    if (j == i) continue;
    int xj = j % HH, yj = j / HH;
    float dx = (float)(xi - xj), dy = (float)(yi - yj);
    s += __builtin_amdgcn_exp2f(-L2E8 * (dx * dx + dy * dy));
  }
  s = wave_sum(s);
  if (lane == 0) rsg[i] = 1.f / sqrtf(s);
}

// K5: bilateral row sums -> colors.w (self term = 1, subtracted)
__global__ void k_rsb(float4* __restrict__ COL, const float2* __restrict__ XY) {
  int b = blockIdx.x;
  int nb = b / NP, i = b % NP;
  int lane = (int)threadIdx.x;
  float4 ci = COL[b];
  float2 xyi = XY[i];
  const float4* colb = COL + (size_t)nb * NP;
  float s = 0.f;
  for (int j = lane; j < NP; j += 64) {
    float4 cj = colb[j];
    float2 xyj = XY[j];
    float dx = xyi.x - xyj.x, dy = xyi.y - xyj.y;
    float acc = dx * dx + dy * dy;
    float e0 = ci.x - cj.x, e1 = ci.y - cj.y, e2 = ci.z - cj.z;
    acc += e0 * e0 + e1 * e1 + e2 * e2;
    s += __builtin_amdgcn_exp2f(-acc);
  }
  s = wave_sum(s) - 1.0f;
  if (lane == 0) ((float*)(COL + b))[3] = 1.f / sqrtf(s);
}

// K6: M[n][i][j] = 10*Kb_norm + 3*Kg_norm (bf16, diag 0), row stride NPAD.
// 5-D distance form, incremental coords, Gaussian under execz-skipped gate.
__global__ __launch_bounds__(256) void k_buildM(const float4* __restrict__ COL,
                                                const float* __restrict__ rsg,
                                                ushort_t* __restrict__ M) {
  int row = blockIdx.x;     // [0, NPIX)
  int nb = row / NP, i = row % NP;
  float4 ci = COL[row];
  float xi = (float)(i % HH) * CS_XY, yi = (float)(i / HH) * CS_XY;
  float sb = 10.f * ci.w;          // 10 * rsb_i
  float sg = 3.f * rsg[i];         // 3 * rsg_i
  const float4* colb = COL + (size_t)nb * NP;
  uint_t* Mrow = (uint_t*)(M + ((size_t)nb * NPAD + i) * NPAD);

  const float XW = 40.5f * CS_XY;     // wrap threshold
  const float X41 = 41.0f * CS_XY;
  int j0 = 2 * (int)threadIdx.x;
  float x0 = (float)(j0 % HH) * CS_XY;
  float y0 = (float)(j0 / HH) * CS_XY;

  for (int p = (int)threadIdx.x; p < NPAD / 2; p += 256) {
    int ja = 2 * p, jb = ja + 1;
    // coords for jb
    float x1 = x0 + CS_XY, y1 = y0;
    if (x1 > XW) { x1 = 0.f; y1 += CS_XY; }

    float va, vb;
    {
      int jc = min(ja, NP - 1);
      float4 cj = colb[jc];
      float dx = xi - x0, dy = yi - y0;
      float axy = dx * dx + dy * dy;
      float e0 = ci.x - cj.x, e1 = ci.y - cj.y, e2 = ci.z - cj.z;
      float acc = axy + e0 * e0 + e1 * e1 + e2 * e2;
      va = __builtin_amdgcn_exp2f(-acc) * (sb * cj.w);
      if (axy < GATE) va += __builtin_amdgcn_exp2f(-KGC * axy) * (sg * rsg[jc]);
      if (ja >= NP || ja == i) va = 0.f;
    }
    {
      int jc = min(jb, NP - 1);
      float4 cj = colb[jc];
      float dx = xi - x1, dy = yi - y1;
      float axy = dx * dx + dy * dy;
      float e0 = ci.x - cj.x, e1 = ci.y - cj.y, e2 = ci.z - cj.z;
      float acc = axy + e0 * e0 + e1 * e1 + e2 * e2;
      vb = __builtin_amdgcn_exp2f(-acc) * (sb * cj.w);
      if (axy < GATE) vb += __builtin_amdgcn_exp2f(-KGC * axy) * (sg * rsg[jc]);
      if (jb >= NP || jb == i) vb = 0.f;
    }
    Mrow[p] = (uint_t)f32_to_bf16(va) | ((uint_t)f32_to_bf16(vb) << 16);

    // advance by 512 pixels: x += 20, y += 12 (+wrap)
    x0 += 20.f * CS_XY; y0 += 12.f * CS_XY;
    if (x0 > XW) { x0 -= X41; y0 += CS_XY; }
  }
}

// K7: one mean-field iteration via MFMA.
// 512 threads = 8 waves = 2 row-tiles (16 rows) x 4 K-split. LDS reduce, dual epilogue.
__global__ __launch_bounds__(512) void k_iter(const ushort_t* __restrict__ M,
                                              const ushort_t* __restrict__ QBin,
                                              ushort_t* __restrict__ QBout,
                                              const float* __restrict__ LOGU,
                                              float* __restrict__ QF) {
  __shared__ float Red[8 * 512];   // 16 KB
  const int nb = blockIdx.x / NBLK;
  const int t0 = (blockIdx.x % NBLK) * RPB;
  const int tid = (int)threadIdx.x;
  const int lane = tid & 63;
  const int wv = tid >> 6;
  const int rt = wv & 1, ks = wv >> 1;
  const int mrow = lane & 15, quad = lane >> 4;

  f32x4 acc0 = {0.f, 0.f, 0.f, 0.f};
  f32x4 acc1 = {0.f, 0.f, 0.f, 0.f};

  const ushort_t* Ap = M + ((size_t)nb * NPAD + t0 + rt * 16 + mrow) * NPAD + ks * 32 + quad * 8;
  const ushort_t* Bp = QBin + (size_t)nb * QB_BATCH + (size_t)ks * 1024 + lane * 8;

  #pragma unroll 2
  for (int kb = ks; kb < NKB; kb += 4) {
    short8 a  = *(const short8*)(Ap);
    short8 b0 = *(const short8*)(Bp);
    short8 b1 = *(const short8*)(Bp + 512);
    Ap += 128; Bp += 4096;
    acc0 = __builtin_amdgcn_mfma_f32_16x16x32_bf16(a, b0, acc0, 0, 0, 0);
    acc1 = __builtin_amdgcn_mfma_f32_16x16x32_bf16(a, b1, acc1, 0, 0, 0);
  }

  #pragma unroll
  for (int c = 0; c < 4; ++c) {
    Red[c * 512 + tid] = acc0[c];
    Red[(4 + c) * 512 + tid] = acc1[c];
  }
  __syncthreads();

  if (wv < 2) {
    const bool c1ok = (mrow + 16) < NCH;
    const int lbase = wv * 64 + lane;
    #pragma unroll
    for (int reg = 0; reg < 4; ++reg) {
      int r = t0 + wv * 16 + quad * 4 + reg;
      int rg = nb * NP + min(r, NP - 1);
      float a0 = Red[reg * 512 + lbase] + Red[reg * 512 + 128 + lbase]
               + Red[reg * 512 + 256 + lbase] + Red[reg * 512 + 384 + lbase];
      float a1 = Red[(4 + reg) * 512 + lbase] + Red[(4 + reg) * 512 + 128 + lbase]
               + Red[(4 + reg) * 512 + 256 + lbase] + Red[(4 + reg) * 512 + 384 + lbase];
      float tv0 = LOGU[(size_t)rg * QS + mrow] + a0;
      float tv1 = c1ok ? (LOGU[(size_t)rg * QS + 16 + mrow] + a1) : -1e30f;
      float mx = fmaxf(tv0, tv1);
      mx = fmaxf(mx, __shfl_xor(mx, 1));
      mx = fmaxf(mx, __shfl_xor(mx, 2));
      mx = fmaxf(mx, __shfl_xor(mx, 4));
      mx = fmaxf(mx, __shfl_xor(mx, 8));
      float e0 = __expf(tv0 - mx);
      float e1 = c1ok ? __expf(tv1 - mx) : 0.f;
      float sm = e0 + e1;
      sm += __shfl_xor(sm, 1);
      sm += __shfl_xor(sm, 2);
      sm += __shfl_xor(sm, 4);
      sm += __shfl_xor(sm, 8);
      float rinv = 1.f / sm;
      if (r < NP) {
        int kb = r >> 5, kr = r & 31, q2 = kr >> 3, j = kr & 7;
        size_t sbo = (size_t)nb * QB_BATCH + (size_t)kb * 1024 + (q2 * 16 + mrow) * 8 + j;
        float q0 = e0 * rinv;
        QF[(size_t)(nb * NP + r) * QS + mrow] = q0;
        QBout[sbo] = f32_to_bf16(q0);
        if (c1ok) {
          float q1 = e1 * rinv;
          QF[(size_t)(nb * NP + r) * QS + 16 + mrow] = q1;
          QBout[sbo + 512] = f32_to_bf16(q1);
        }
      }
    }
  }
}

// K8: per-pixel loss contribution, block-reduced partials
__global__ void k_loss(const float* __restrict__ Qf, const float* __restrict__ P,
                       float* __restrict__ part) {
  int t = blockIdx.x * blockDim.x + threadIdx.x;
  float s = 0.f;
  if (t < NPIX) {
    const float* q = Qf + (size_t)t * QS;
    const float* p = P + (size_t)t * QS;
    float qv[NCH];
    float qsum = 0.f;
    #pragma unroll
    for (int c = 0; c < NCH; ++c) { qv[c] = fmaxf(q[c], EPSV); qsum += qv[c]; }
    float r = 1.f / qsum;
    #pragma unroll
    for (int c = 0; c < NCH; ++c) {
      float qs = qv[c] * r;
      float ratio = fminf(fmaxf(qs / p[c], 0.05f), 20.0f);
      s += qs * logf(ratio);
    }
  }
  __shared__ float red[256];
  red[threadIdx.x] = s;
  __syncthreads();
  for (int st = 128; st > 0; st >>= 1) {
    if ((int)threadIdx.x < st) red[threadIdx.x] += red[threadIdx.x + st];
    __syncthreads();
  }
  if (threadIdx.x == 0) part[blockIdx.x] = red[0];
}

// K9: final reduction -> d_out[0]
__global__ void k_final(const float* __restrict__ part, float* __restrict__ out) {
  float s = 0.f;
  for (int k = threadIdx.x; k < LOSS_BLOCKS; k += 64) s += part[k];
  s = wave_sum(s);
  if (threadIdx.x == 0) out[0] = s / (float)NPIX;
}

}  // namespace

extern "C" void kernel_launch(void* const* d_in, const int* in_sizes, int n_in,
                              void* d_out, int out_size, void* d_ws, size_t ws_size,
                              hipStream_t stream) {
  const float* images  = (const float*)d_in[0];   // (16,3,321,321) fp32
  const float* predict = (const float*)d_in[1];   // (16,21,41,41) fp32
  float* out = (float*)d_out;
  float* ws = (float*)d_ws;

  float*  W    = ws + OFF_W;
  float*  RX   = ws + OFF_RX;
  float4* COL  = (float4*)(ws + OFF_COL);
  float*  P    = ws + OFF_P;
  float*  LOGU = ws + OFF_LOGU;
  float*  QF   = ws + OFF_QF;
  float*  RSG  = ws + OFF_RSG;
  float2* XY   = (float2*)(ws + OFF_XY);
  float*  PART = ws + OFF_PART;
  ushort_t* QB_A = (ushort_t*)(ws + OFF_QB);
  ushort_t* QB_B = QB_A + (size_t)QB_BUF;
  ushort_t* M    = (ushort_t*)(ws + OFF_M);

  hipLaunchKernelGGL(k_zero, dim3((unsigned)((QB_ZERO_DWORDS + 255) / 256)), dim3(256), 0,
                     stream, (uint_t*)QB_A);
  hipLaunchKernelGGL(k_weights, dim3(1), dim3(64), 0, stream, W);
  hipLaunchKernelGGL(k_xy, dim3((NPAD + 255) / 256), dim3(256), 0, stream, XY);
  hipLaunchKernelGGL(k_resize_x, dim3((RXN + 255) / 256), dim3(256), 0, stream, images, W, RX);
  hipLaunchKernelGGL(k_resize_y, dim3(LOSS_BLOCKS), dim3(256), 0, stream, RX, W, (float*)COL);
  hipLaunchKernelGGL(k_probs, dim3(LOSS_BLOCKS), dim3(256), 0, stream, predict, P, LOGU, QB_A);
  hipLaunchKernelGGL(k_rsg, dim3(NP), dim3(64), 0, stream, RSG);
  hipLaunchKernelGGL(k_rsb, dim3(NPIX), dim3(64), 0, stream, COL, XY);
  hipLaunchKernelGGL(k_buildM, dim3(NPIX), dim3(256), 0, stream, COL, RSG, M);

  const ushort_t* qbin = QB_A;
  ushort_t* qbout = QB_B;
  for (int it = 0; it < 10; ++it) {
    hipLaunchKernelGGL(k_iter, dim3(NBATCH * NBLK), dim3(512), 0, stream,
                       M, qbin, qbout, LOGU, QF);
    const ushort_t* t = qbout; qbout = (ushort_t*)qbin; qbin = t;
  }
  hipLaunchKernelGGL(k_loss, dim3(LOSS_BLOCKS), dim3(256), 0, stream, QF, P, PART);
  hipLaunchKernelGGL(k_final, dim3(1), dim3(64), 0, stream, PART, out);
}

// Round 5
// 465.151 us; speedup vs baseline: 1.8626x; 1.0244x over previous
//
#include <hip/hip_runtime.h>
#include <math.h>

namespace {

typedef unsigned short ushort_t;
typedef unsigned int uint_t;
typedef __attribute__((ext_vector_type(8))) short short8;
typedef __attribute__((ext_vector_type(4))) float f32x4;

constexpr int NBATCH = 16;
constexpr int NCH    = 21;
constexpr int HH     = 41;
constexpr int NP     = HH * HH;       // 1681 pixels
constexpr int IW     = 321;           // input image H=W
constexpr int QS     = 32;            // padded channel stride for P/LOGU/QF
constexpr float EPSV = 1e-5f;

constexpr int NPAD   = 1696;          // NP padded to 53*32
constexpr int NKB    = 53;            // K blocks of 32
constexpr int RPB    = 32;            // rows per k_iter / buildM block
constexpr int NBLK   = NPAD / RPB;    // 53 row-blocks per batch
constexpr int NPIX   = NBATCH * NP;             // 26896
constexpr int LOSS_BLOCKS = (NPIX + 255) / 256; // 106
constexpr int RSB_TILES = (NP + 63) / 64;       // 27

// B-fragment-linear Q storage: per batch [53 kb][2 ct][64 lane][8 j] bf16
constexpr int QB_BATCH = NKB * 2 * 512;          // 54272 ushorts per batch
constexpr int QB_BUF   = NBATCH * QB_BATCH;      // 868352 ushorts per buffer
constexpr int RXN = NBATCH * 3 * IW * HH;        // 631728

// 5-D distance scaling: exp(-0.01125*d2 - cd2/338) == exp2(-(|scaled xy diff|^2+|scaled col diff|^2))
constexpr float CS_COLOR = 0.06533245f;   // sqrt(log2(e)/338)
constexpr float CS_XY    = 0.12739827f;   // sqrt(0.01125*log2(e))
constexpr float KGC      = 711.111111f;   // 8/0.01125 : exp(-8*d2)=exp2(-KGC*axy)
constexpr float L2E8     = 11.5415603f;   // 8*log2(e)
constexpr float GATE     = 0.138f;        // axy threshold ~ d2<=8 (dropped kg < 1e-25)

// workspace offsets in floats
constexpr size_t OFF_W    = 0;                   // 13184
constexpr size_t OFF_RX   = 13184;               // 631744
constexpr size_t OFF_COL  = 644928;              // scaled colors+rsb.w [npix][4]
constexpr size_t OFF_P    = 752512;              // 860672
constexpr size_t OFF_LOGU = 1613184;             // 860672
constexpr size_t OFF_QF   = 2473856;             // 860672
constexpr size_t OFF_RSG  = 3334528;             // 1728
constexpr size_t OFF_XY   = 3336256;             // 3456 (NPAD float2)
constexpr size_t OFF_PART = 3339712;             // 256
constexpr size_t OFF_QB   = 3339968;             // 2 buffers * 434176 floats
constexpr size_t OFF_M    = 4208320;             // bf16 M [16][1696][1696]
// total ~107.8 MB

constexpr size_t QB_ZERO_DWORDS = (size_t)QB_BUF;  // both buffers, in dwords

__device__ __forceinline__ float wave_sum(float v) {
  #pragma unroll
  for (int off = 32; off > 0; off >>= 1) v += __shfl_down(v, off, 64);
  return v;
}

__device__ __forceinline__ ushort_t f32_to_bf16(float f) {
  union { float f; uint_t u; } v; v.f = f;
  uint_t r = (v.u + 0x7fffu + ((v.u >> 16) & 1u)) >> 16;   // RTN-even
  return (ushort_t)r;
}

__global__ void k_zero(uint_t* __restrict__ p) {
  size_t t = (size_t)blockIdx.x * blockDim.x + threadIdx.x;
  if (t < QB_ZERO_DWORDS) p[t] = 0u;
}

// K1: jax.image.resize 'linear' (antialias) weight matrix, 321 -> 41.
__global__ void k_weights(float* __restrict__ W) {
  int o = threadIdx.x;
  if (o >= HH) return;
  const float inv = (float)IW / (float)HH;
  float s = (o + 0.5f) * inv - 0.5f;
  float tot = 0.f;
  for (int i = 0; i < IW; ++i) {
    float x = fabsf(s - (float)i) / inv;
    tot += fmaxf(0.f, 1.f - x);
  }
  float r = 1.f / tot;
  for (int i = 0; i < IW; ++i) {
    float x = fabsf(s - (float)i) / inv;
    W[o * IW + i] = fmaxf(0.f, 1.f - x) * r;
  }
}

// scaled pixel-grid coordinate table
__global__ void k_xy(float2* __restrict__ XY) {
  int j = blockIdx.x * blockDim.x + threadIdx.x;
  if (j >= NPAD) return;
  if (j < NP) XY[j] = make_float2((float)(j % HH) * CS_XY, (float)(j / HH) * CS_XY);
  else        XY[j] = make_float2(1e4f, 1e4f);
}

// K2a: separable resize, x pass
__global__ void k_resize_x(const float* __restrict__ img, const float* __restrict__ W,
                           float* __restrict__ RX) {
  int t = blockIdx.x * blockDim.x + threadIdx.x;
  if (t >= RXN) return;
  int xo = t % HH;
  int rest = t / HH;
  int y = rest % IW;
  int nc = rest / IW;
  const float inv = (float)IW / (float)HH;
  float sx = (xo + 0.5f) * inv - 0.5f;
  int xlo = max(0, (int)ceilf(sx - inv)), xhi = min(IW - 1, (int)floorf(sx + inv));
  const float* base = img + ((size_t)nc * IW + y) * IW;
  const float* wr = W + xo * IW;
  float a = 0.f;
  for (int ix = xlo; ix <= xhi; ++ix) a += wr[ix] * base[ix];
  RX[t] = a;
}

// K2b: y pass -> SCALED colors [n][p][4] (w=0, later filled with rsb)
__global__ void k_resize_y(const float* __restrict__ RX, const float* __restrict__ W,
                           float* __restrict__ colors) {
  int t = blockIdx.x * blockDim.x + threadIdx.x;
  if (t >= NPIX) return;
  int nb = t / NP, p = t % NP;
  int yo = p / HH, xo = p % HH;
  const float inv = (float)IW / (float)HH;
  float sy = (yo + 0.5f) * inv - 0.5f;
  int ylo = max(0, (int)ceilf(sy - inv)), yhi = min(IW - 1, (int)floorf(sy + inv));
  const float* wr = W + yo * IW;
  float a0 = 0.f, a1 = 0.f, a2 = 0.f;
  const float* b0 = RX + (size_t)(nb * 3 + 0) * IW * HH + xo;
  const float* b1 = RX + (size_t)(nb * 3 + 1) * IW * HH + xo;
  const float* b2 = RX + (size_t)(nb * 3 + 2) * IW * HH + xo;
  for (int iy = ylo; iy <= yhi; ++iy) {
    float wy = wr[iy];
    a0 += wy * b0[(size_t)iy * HH];
    a1 += wy * b1[(size_t)iy * HH];
    a2 += wy * b2[(size_t)iy * HH];
  }
  float* c = colors + (size_t)t * 4;
  c[0] = a0 * CS_COLOR; c[1] = a1 * CS_COLOR; c[2] = a2 * CS_COLOR; c[3] = 0.f;
}

// K3: clamped channel softmax -> P, LOGU, initial bf16 B-fragments
__global__ void k_probs(const float* __restrict__ pred, float* __restrict__ P,
                        float* __restrict__ LOGU, ushort_t* __restrict__ QB) {
  int t = blockIdx.x * blockDim.x + threadIdx.x;
  if (t >= NPIX) return;
  int nb = t / NP, i = t % NP;
  const float* src = pred + (size_t)nb * NCH * NP + i;
  float v[NCH];
  float m = -1e30f;
  #pragma unroll
  for (int c = 0; c < NCH; ++c) { v[c] = src[(size_t)c * NP]; m = fmaxf(m, v[c]); }
  float s = 0.f;
  #pragma unroll
  for (int c = 0; c < NCH; ++c) { v[c] = expf(v[c] - m); s += v[c]; }
  float r = 1.f / s;
  float s2 = 0.f;
  #pragma unroll
  for (int c = 0; c < NCH; ++c) { v[c] = fminf(fmaxf(v[c] * r, EPSV), 1.0f); s2 += v[c]; }
  float r2 = 1.f / s2;
  float* dp = P + (size_t)t * QS;
  float* dl = LOGU + (size_t)t * QS;
  int kb = i >> 5, kr = i & 31, q2 = kr >> 3, j = kr & 7;
  size_t sb = (size_t)nb * QB_BATCH + (size_t)kb * 1024 + j;
  #pragma unroll
  for (int c = 0; c < NCH; ++c) {
    float p = v[c] * r2;
    dp[c] = p; dl[c] = logf(p);
    int ct = c >> 4;
    QB[sb + (size_t)ct * 512 + (q2 * 16 + (c & 15)) * 8] = f32_to_bf16(p);
  }
}

// K4: Gaussian row sums: rsg[i] = 1/sqrt(sum_{j!=i} exp(-8*d2))
__global__ void k_rsg(float* __restrict__ rsg) {
  int i = blockIdx.x;
  int lane = threadIdx.x;
  int xi = i % HH, yi = i / HH;
  float s = 0.f;
  for (int j = lane; j < NP; j += 64) {
    if (j == i) continue;
    int xj = j % HH, yj = j / HH;
    float dx = (float)(xi - xj), dy = (float)(yi - yj);
    s += __builtin_amdgcn_exp2f(-L2E8 * (dx * dx + dy * dy));
  }
  s = wave_sum(s);
  if (lane == 0) rsg[i] = 1.f / sqrtf(s);
}

// K5: bilateral row sums -> colors.w. LDS-tiled: block = 64 i's, 8 j-split waves.
// j-loop LDS reads are wave-uniform broadcasts (conflict-free).
__global__ __launch_bounds__(512) void k_rsb(float4* __restrict__ COL,
                                             const float2* __restrict__ XY) {
  __shared__ float S8[NP * 8];     // [j][c0,c1,c2,-,x,y,-,-] 53.8 KB
  __shared__ float Red2[8 * 64];
  const int nb = blockIdx.x / RSB_TILES;
  const int i0 = (blockIdx.x % RSB_TILES) * 64;
  const int tid = (int)threadIdx.x;
  const int lane = tid & 63, wv = tid >> 6;

  const float4* colb = COL + (size_t)nb * NP;
  for (int j = tid; j < NP; j += 512) {
    float4 c = colb[j];
    float2 xy = XY[j];
    *(float4*)&S8[j * 8]     = make_float4(c.x, c.y, c.z, 0.f);
    *(float4*)&S8[j * 8 + 4] = make_float4(xy.x, xy.y, 0.f, 0.f);
  }
  __syncthreads();

  const int i = i0 + lane;
  const int im = min(i, NP - 1);
  const float ci0 = S8[im * 8], ci1 = S8[im * 8 + 1], ci2 = S8[im * 8 + 2];
  const float xi = S8[im * 8 + 4], yi = S8[im * 8 + 5];

  float s = 0.f;
  for (int j = wv; j < NP; j += 8) {
    float4 a = *(const float4*)&S8[j * 8];       // broadcast
    float4 b = *(const float4*)&S8[j * 8 + 4];
    float dx = xi - b.x, dy = yi - b.y;
    float acc = dx * dx;
    acc = fmaf(dy, dy, acc);
    float e0 = ci0 - a.x, e1 = ci1 - a.y, e2 = ci2 - a.z;
    acc = fmaf(e0, e0, acc);
    acc = fmaf(e1, e1, acc);
    acc = fmaf(e2, e2, acc);
    s += __builtin_amdgcn_exp2f(-acc);
  }
  Red2[wv * 64 + lane] = s;
  __syncthreads();
  if (wv == 0 && i < NP) {
    float t = -1.0f;   // remove self term exp2(0)=1
    #pragma unroll
    for (int w = 0; w < 8; ++w) t += Red2[w * 64 + lane];
    ((float*)(COL + (size_t)nb * NP + i))[3] = 1.f / sqrtf(t);
  }
}

// K6: M[n][i][j] = 10*Kb_norm + 3*Kg_norm (bf16, diag 0), row stride NPAD.
// LDS-tiled: block = 32 rows of one batch; stage COL/XY/rsg once (stride-7 entries).
__global__ __launch_bounds__(256) void k_buildM(const float4* __restrict__ COL,
                                                const float2* __restrict__ XY,
                                                const float* __restrict__ rsg,
                                                ushort_t* __restrict__ M) {
  __shared__ float S7[NP * 7];    // [j][c0,c1,c2,rsb,x,y,rsg] 47 KB
  const int nb = blockIdx.x / NBLK;
  const int i0 = (blockIdx.x % NBLK) * RPB;
  const int tid = (int)threadIdx.x;

  const float4* colb = COL + (size_t)nb * NP;
  for (int j = tid; j < NP; j += 256) {
    float4 c = colb[j];
    float2 xy = XY[j];
    float* e = &S7[j * 7];
    e[0] = c.x; e[1] = c.y; e[2] = c.z; e[3] = c.w;
    e[4] = xy.x; e[5] = xy.y; e[6] = rsg[j];
  }
  __syncthreads();

  for (int r = 0; r < RPB; ++r) {
    const int i = i0 + r;
    if (i >= NP) break;
    const float* ei = &S7[i * 7];
    const float ci0 = ei[0], ci1 = ei[1], ci2 = ei[2];
    const float sb = 10.f * ei[3], xi = ei[4], yi = ei[5], sg = 3.f * ei[6];
    ushort_t* Mrow = M + ((size_t)nb * NPAD + i) * NPAD;
    for (int j = tid; j < NPAD; j += 256) {
      float val = 0.f;
      if (j < NP) {
        const float* e = &S7[j * 7];
        float dx = xi - e[4], dy = yi - e[5];
        float axy = fmaf(dy, dy, dx * dx);
        float e0 = ci0 - e[0], e1 = ci1 - e[1], e2 = ci2 - e[2];
        float acc = axy;
        acc = fmaf(e0, e0, acc);
        acc = fmaf(e1, e1, acc);
        acc = fmaf(e2, e2, acc);
        val = __builtin_amdgcn_exp2f(-acc) * (sb * e[3]);
        if (axy < GATE) val = fmaf(__builtin_amdgcn_exp2f(-KGC * axy), sg * e[6], val);
        if (j == i) val = 0.f;
      }
      Mrow[j] = f32_to_bf16(val);
    }
  }
}

// K7: one mean-field iteration via MFMA.
// 512 threads = 8 waves, 8-way K-split; each wave computes BOTH 16-row tiles
// (4 accs, 4 loads + 4 MFMA per kb) -> zero B duplication. LDS reduce, 2-wave epilogue.
__global__ __launch_bounds__(512) void k_iter(const ushort_t* __restrict__ M,
                                              const ushort_t* __restrict__ QBin,
                                              ushort_t* __restrict__ QBout,
                                              const float* __restrict__ LOGU,
                                              float* __restrict__ QF) {
  __shared__ float Red[16 * 512];   // 32 KB
  const int nb = blockIdx.x / NBLK;
  const int t0 = (blockIdx.x % NBLK) * RPB;
  const int tid = (int)threadIdx.x;
  const int lane = tid & 63;
  const int ks = tid >> 6;              // 0..7 K-split
  const int mrow = lane & 15, quad = lane >> 4;

  f32x4 acc00 = {0.f, 0.f, 0.f, 0.f};  // tile0 x ct0
  f32x4 acc01 = {0.f, 0.f, 0.f, 0.f};  // tile0 x ct1
  f32x4 acc10 = {0.f, 0.f, 0.f, 0.f};  // tile1 x ct0
  f32x4 acc11 = {0.f, 0.f, 0.f, 0.f};  // tile1 x ct1

  const ushort_t* Ap0 = M + ((size_t)nb * NPAD + t0 + mrow) * NPAD + (size_t)ks * 32 + quad * 8;
  const ushort_t* Ap1 = Ap0 + (size_t)16 * NPAD;
  const ushort_t* Bp = QBin + (size_t)nb * QB_BATCH + (size_t)ks * 1024 + lane * 8;

  #pragma unroll 2
  for (int kb = ks; kb < NKB; kb += 8) {
    short8 a0 = *(const short8*)(Ap0);
    short8 a1 = *(const short8*)(Ap1);
    short8 b0 = *(const short8*)(Bp);
    short8 b1 = *(const short8*)(Bp + 512);
    Ap0 += 256; Ap1 += 256; Bp += 8192;
    acc00 = __builtin_amdgcn_mfma_f32_16x16x32_bf16(a0, b0, acc00, 0, 0, 0);
    acc01 = __builtin_amdgcn_mfma_f32_16x16x32_bf16(a0, b1, acc01, 0, 0, 0);
    acc10 = __builtin_amdgcn_mfma_f32_16x16x32_bf16(a1, b0, acc10, 0, 0, 0);
    acc11 = __builtin_amdgcn_mfma_f32_16x16x32_bf16(a1, b1, acc11, 0, 0, 0);
  }

  #pragma unroll
  for (int c = 0; c < 4; ++c) {
    Red[(c) * 512 + tid]      = acc00[c];
    Red[(4 + c) * 512 + tid]  = acc01[c];
    Red[(8 + c) * 512 + tid]  = acc10[c];
    Red[(12 + c) * 512 + tid] = acc11[c];
  }
  __syncthreads();

  const int wv = ks;
  if (wv < 2) {
    const bool c1ok = (mrow + 16) < NCH;
    #pragma unroll
    for (int reg = 0; reg < 4; ++reg) {
      int r = t0 + wv * 16 + quad * 4 + reg;
      int rg = nb * NP + min(r, NP - 1);
      float a0 = 0.f, a1 = 0.f;
      #pragma unroll
      for (int k8 = 0; k8 < 8; ++k8) {
        a0 += Red[(wv * 8 + reg) * 512 + k8 * 64 + lane];
        a1 += Red[(wv * 8 + 4 + reg) * 512 + k8 * 64 + lane];
      }
      float tv0 = LOGU[(size_t)rg * QS + mrow] + a0;
      float tv1 = c1ok ? (LOGU[(size_t)rg * QS + 16 + mrow] + a1) : -1e30f;
      float mx = fmaxf(tv0, tv1);
      mx = fmaxf(mx, __shfl_xor(mx, 1));
      mx = fmaxf(mx, __shfl_xor(mx, 2));
      mx = fmaxf(mx, __shfl_xor(mx, 4));
      mx = fmaxf(mx, __shfl_xor(mx, 8));
      float e0 = __expf(tv0 - mx);
      float e1 = c1ok ? __expf(tv1 - mx) : 0.f;
      float sm = e0 + e1;
      sm += __shfl_xor(sm, 1);
      sm += __shfl_xor(sm, 2);
      sm += __shfl_xor(sm, 4);
      sm += __shfl_xor(sm, 8);
      float rinv = 1.f / sm;
      if (r < NP) {
        int kb = r >> 5, kr = r & 31, q2 = kr >> 3, j = kr & 7;
        size_t sbo = (size_t)nb * QB_BATCH + (size_t)kb * 1024 + (q2 * 16 + mrow) * 8 + j;
        float q0 = e0 * rinv;
        QF[(size_t)(nb * NP + r) * QS + mrow] = q0;
        QBout[sbo] = f32_to_bf16(q0);
        if (c1ok) {
          float q1 = e1 * rinv;
          QF[(size_t)(nb * NP + r) * QS + 16 + mrow] = q1;
          QBout[sbo + 512] = f32_to_bf16(q1);
        }
      }
    }
  }
}

// K8: per-pixel loss contribution, block-reduced partials
__global__ void k_loss(const float* __restrict__ Qf, const float* __restrict__ P,
                       float* __restrict__ part) {
  int t = blockIdx.x * blockDim.x + threadIdx.x;
  float s = 0.f;
  if (t < NPIX) {
    const float* q = Qf + (size_t)t * QS;
    const float* p = P + (size_t)t * QS;
    float qv[NCH];
    float qsum = 0.f;
    #pragma unroll
    for (int c = 0; c < NCH; ++c) { qv[c] = fmaxf(q[c], EPSV); qsum += qv[c]; }
    float r = 1.f / qsum;
    #pragma unroll
    for (int c = 0; c < NCH; ++c) {
      float qs = qv[c] * r;
      float ratio = fminf(fmaxf(qs / p[c], 0.05f), 20.0f);
      s += qs * logf(ratio);
    }
  }
  __shared__ float red[256];
  red[threadIdx.x] = s;
  __syncthreads();
  for (int st = 128; st > 0; st >>= 1) {
    if ((int)threadIdx.x < st) red[threadIdx.x] += red[threadIdx.x + st];
    __syncthreads();
  }
  if (threadIdx.x == 0) part[blockIdx.x] = red[0];
}

// K9: final reduction -> d_out[0]
__global__ void k_final(const float* __restrict__ part, float* __restrict__ out) {
  float s = 0.f;
  for (int k = threadIdx.x; k < LOSS_BLOCKS; k += 64) s += part[k];
  s = wave_sum(s);
  if (threadIdx.x == 0) out[0] = s / (float)NPIX;
}

}  // namespace

extern "C" void kernel_launch(void* const* d_in, const int* in_sizes, int n_in,
                              void* d_out, int out_size, void* d_ws, size_t ws_size,
                              hipStream_t stream) {
  const float* images  = (const float*)d_in[0];   // (16,3,321,321) fp32
  const float* predict = (const float*)d_in[1];   // (16,21,41,41) fp32
  float* out = (float*)d_out;
  float* ws = (float*)d_ws;

  float*  W    = ws + OFF_W;
  float*  RX   = ws + OFF_RX;
  float4* COL  = (float4*)(ws + OFF_COL);
  float*  P    = ws + OFF_P;
  float*  LOGU = ws + OFF_LOGU;
  float*  QF   = ws + OFF_QF;
  float*  RSG  = ws + OFF_RSG;
  float2* XY   = (float2*)(ws + OFF_XY);
  float*  PART = ws + OFF_PART;
  ushort_t* QB_A = (ushort_t*)(ws + OFF_QB);
  ushort_t* QB_B = QB_A + (size_t)QB_BUF;
  ushort_t* M    = (ushort_t*)(ws + OFF_M);

  hipLaunchKernelGGL(k_zero, dim3((unsigned)((QB_ZERO_DWORDS + 255) / 256)), dim3(256), 0,
                     stream, (uint_t*)QB_A);
  hipLaunchKernelGGL(k_weights, dim3(1), dim3(64), 0, stream, W);
  hipLaunchKernelGGL(k_xy, dim3((NPAD + 255) / 256), dim3(256), 0, stream, XY);
  hipLaunchKernelGGL(k_resize_x, dim3((RXN + 255) / 256), dim3(256), 0, stream, images, W, RX);
  hipLaunchKernelGGL(k_resize_y, dim3(LOSS_BLOCKS), dim3(256), 0, stream, RX, W, (float*)COL);
  hipLaunchKernelGGL(k_probs, dim3(LOSS_BLOCKS), dim3(256), 0, stream, predict, P, LOGU, QB_A);
  hipLaunchKernelGGL(k_rsg, dim3(NP), dim3(64), 0, stream, RSG);
  hipLaunchKernelGGL(k_rsb, dim3(NBATCH * RSB_TILES), dim3(512), 0, stream, COL, XY);
  hipLaunchKernelGGL(k_buildM, dim3(NBATCH * NBLK), dim3(256), 0, stream, COL, XY, RSG, M);

  const ushort_t* qbin = QB_A;
  ushort_t* qbout = QB_B;
  for (int it = 0; it < 10; ++it) {
    hipLaunchKernelGGL(k_iter, dim3(NBATCH * NBLK), dim3(512), 0, stream,
                       M, qbin, qbout, LOGU, QF);
    const ushort_t* t = qbout; qbout = (ushort_t*)qbin; qbin = t;
  }
  hipLaunchKernelGGL(k_loss, dim3(LOSS_BLOCKS), dim3(256), 0, stream, QF, P, PART);
  hipLaunchKernelGGL(k_final, dim3(1), dim3(64), 0, stream, PART, out);
}

// Round 6
// 417.343 us; speedup vs baseline: 2.0760x; 1.1146x over previous
//
#include <hip/hip_runtime.h>
#include <math.h>

namespace {

typedef unsigned short ushort_t;
typedef unsigned int uint_t;
typedef __attribute__((ext_vector_type(8))) short short8;
typedef __attribute__((ext_vector_type(4))) float f32x4;

constexpr int NBATCH = 16;
constexpr int NCH    = 21;
constexpr int HH     = 41;
constexpr int NP     = HH * HH;       // 1681 pixels
constexpr int IW     = 321;           // input image H=W
constexpr int QS     = 32;            // padded channel stride for P/LOGU/QF
constexpr float EPSV = 1e-5f;

constexpr int NROWS  = 1696;          // M rows per batch (row-tile pad)
constexpr int KPAD   = 1792;          // M cols padded to 56*32 (7 chunks of 256)
constexpr int NKB2   = 56;            // padded K blocks of 32
constexpr int ITL    = 27;            // 64-row tiles per batch (rows to 1727, guarded)
constexpr int NPIX   = NBATCH * NP;             // 26896
constexpr int LOSS_BLOCKS = (NPIX + 255) / 256; // 106
constexpr int RSB_TILES = (NP + 63) / 64;       // 27

// B-fragment-linear Q storage: per batch [56 kb][2 ct][64 lane][8 j] bf16 (kb>=53 zero)
constexpr int QB_BATCH = NKB2 * 2 * 512;         // 57344 ushorts per batch
constexpr int QB_BUF   = NBATCH * QB_BATCH;      // 917504 ushorts per buffer
constexpr int RXN = NBATCH * 3 * IW * HH;        // 631728

// 5-D distance scaling: exp(-0.01125*d2 - cd2/338) == exp2(-(|scaled xy diff|^2+|scaled col diff|^2))
constexpr float CS_COLOR = 0.06533245f;   // sqrt(log2(e)/338)
constexpr float CS_XY    = 0.12739827f;   // sqrt(0.01125*log2(e))
constexpr float KGC      = 711.111111f;   // 8/0.01125 : exp(-8*d2)=exp2(-KGC*axy)
constexpr float L2E8     = 11.5415603f;   // 8*log2(e)
constexpr float GATE     = 0.138f;        // axy threshold ~ d2<=8 (dropped kg < 1e-25)

// workspace offsets in floats
constexpr size_t OFF_W    = 0;                   // 13184
constexpr size_t OFF_RX   = 13184;               // 631744
constexpr size_t OFF_COL  = 644928;              // scaled colors+rsb.w [npix][4]
constexpr size_t OFF_P    = 752512;              // 860672
constexpr size_t OFF_LOGU = 1613184;             // 860672
constexpr size_t OFF_QF   = 2473856;             // 860672
constexpr size_t OFF_RSG  = 3334528;             // 1728
constexpr size_t OFF_XY   = 3336256;             // 3456 (float2)
constexpr size_t OFF_PART = 3339712;             // 256
constexpr size_t OFF_QB   = 3339968;             // 2 buffers * 917504 ushorts = 917504 floats
constexpr size_t OFF_M    = 4257472;             // bf16 M [16][1696 rows][1792 cols]
// total = 4257472 + 24313856 = 28,571,328 floats ~ 114.3 MB (ws proven >= ~195 MB in round 1)

constexpr size_t QB_ZERO_DWORDS = (size_t)QB_BUF;  // both buffers, in dwords

#define GLOAD_LDS16(g, l)                                                              \
  __builtin_amdgcn_global_load_lds((const __attribute__((address_space(1))) uint_t*)(g), \
                                   (__attribute__((address_space(3))) uint_t*)(l), 16, 0, 0)

__device__ __forceinline__ float wave_sum(float v) {
  #pragma unroll
  for (int off = 32; off > 0; off >>= 1) v += __shfl_down(v, off, 64);
  return v;
}

__device__ __forceinline__ ushort_t f32_to_bf16(float f) {
  union { float f; uint_t u; } v; v.f = f;
  uint_t r = (v.u + 0x7fffu + ((v.u >> 16) & 1u)) >> 16;   // RTN-even
  return (ushort_t)r;
}

__global__ void k_zero(uint_t* __restrict__ p) {
  size_t t = (size_t)blockIdx.x * blockDim.x + threadIdx.x;
  if (t < QB_ZERO_DWORDS) p[t] = 0u;
}

// K1: jax.image.resize 'linear' (antialias) weight matrix, 321 -> 41.
__global__ void k_weights(float* __restrict__ W) {
  int o = threadIdx.x;
  if (o >= HH) return;
  const float inv = (float)IW / (float)HH;
  float s = (o + 0.5f) * inv - 0.5f;
  float tot = 0.f;
  for (int i = 0; i < IW; ++i) {
    float x = fabsf(s - (float)i) / inv;
    tot += fmaxf(0.f, 1.f - x);
  }
  float r = 1.f / tot;
  for (int i = 0; i < IW; ++i) {
    float x = fabsf(s - (float)i) / inv;
    W[o * IW + i] = fmaxf(0.f, 1.f - x) * r;
  }
}

// scaled pixel-grid coordinate table (for k_rsb)
__global__ void k_xy(float2* __restrict__ XY) {
  int j = blockIdx.x * blockDim.x + threadIdx.x;
  if (j >= NP) return;
  XY[j] = make_float2((float)(j % HH) * CS_XY, (float)(j / HH) * CS_XY);
}

// K2a: separable resize, x pass
__global__ void k_resize_x(const float* __restrict__ img, const float* __restrict__ W,
                           float* __restrict__ RX) {
  int t = blockIdx.x * blockDim.x + threadIdx.x;
  if (t >= RXN) return;
  int xo = t % HH;
  int rest = t / HH;
  int y = rest % IW;
  int nc = rest / IW;
  const float inv = (float)IW / (float)HH;
  float sx = (xo + 0.5f) * inv - 0.5f;
  int xlo = max(0, (int)ceilf(sx - inv)), xhi = min(IW - 1, (int)floorf(sx + inv));
  const float* base = img + ((size_t)nc * IW + y) * IW;
  const float* wr = W + xo * IW;
  float a = 0.f;
  for (int ix = xlo; ix <= xhi; ++ix) a += wr[ix] * base[ix];
  RX[t] = a;
}

// K2b: y pass -> SCALED colors [n][p][4] (w=0, later filled with rsb)
__global__ void k_resize_y(const float* __restrict__ RX, const float* __restrict__ W,
                           float* __restrict__ colors) {
  int t = blockIdx.x * blockDim.x + threadIdx.x;
  if (t >= NPIX) return;
  int nb = t / NP, p = t % NP;
  int yo = p / HH, xo = p % HH;
  const float inv = (float)IW / (float)HH;
  float sy = (yo + 0.5f) * inv - 0.5f;
  int ylo = max(0, (int)ceilf(sy - inv)), yhi = min(IW - 1, (int)floorf(sy + inv));
  const float* wr = W + yo * IW;
  float a0 = 0.f, a1 = 0.f, a2 = 0.f;
  const float* b0 = RX + (size_t)(nb * 3 + 0) * IW * HH + xo;
  const float* b1 = RX + (size_t)(nb * 3 + 1) * IW * HH + xo;
  const float* b2 = RX + (size_t)(nb * 3 + 2) * IW * HH + xo;
  for (int iy = ylo; iy <= yhi; ++iy) {
    float wy = wr[iy];
    a0 += wy * b0[(size_t)iy * HH];
    a1 += wy * b1[(size_t)iy * HH];
    a2 += wy * b2[(size_t)iy * HH];
  }
  float* c = colors + (size_t)t * 4;
  c[0] = a0 * CS_COLOR; c[1] = a1 * CS_COLOR; c[2] = a2 * CS_COLOR; c[3] = 0.f;
}

// K3: clamped channel softmax -> P, LOGU, initial bf16 B-fragments
__global__ void k_probs(const float* __restrict__ pred, float* __restrict__ P,
                        float* __restrict__ LOGU, ushort_t* __restrict__ QB) {
  int t = blockIdx.x * blockDim.x + threadIdx.x;
  if (t >= NPIX) return;
  int nb = t / NP, i = t % NP;
  const float* src = pred + (size_t)nb * NCH * NP + i;
  float v[NCH];
  float m = -1e30f;
  #pragma unroll
  for (int c = 0; c < NCH; ++c) { v[c] = src[(size_t)c * NP]; m = fmaxf(m, v[c]); }
  float s = 0.f;
  #pragma unroll
  for (int c = 0; c < NCH; ++c) { v[c] = expf(v[c] - m); s += v[c]; }
  float r = 1.f / s;
  float s2 = 0.f;
  #pragma unroll
  for (int c = 0; c < NCH; ++c) { v[c] = fminf(fmaxf(v[c] * r, EPSV), 1.0f); s2 += v[c]; }
  float r2 = 1.f / s2;
  float* dp = P + (size_t)t * QS;
  float* dl = LOGU + (size_t)t * QS;
  int kb = i >> 5, kr = i & 31, q2 = kr >> 3, j = kr & 7;
  size_t sb = (size_t)nb * QB_BATCH + (size_t)kb * 1024 + j;
  #pragma unroll
  for (int c = 0; c < NCH; ++c) {
    float p = v[c] * r2;
    dp[c] = p; dl[c] = logf(p);
    int ct = c >> 4;
    QB[sb + (size_t)ct * 512 + (q2 * 16 + (c & 15)) * 8] = f32_to_bf16(p);
  }
}

// K4: Gaussian row sums: rsg[i] = 1/sqrt(sum_{j!=i} exp(-8*d2))
__global__ void k_rsg(float* __restrict__ rsg) {
  int i = blockIdx.x;
  int lane = threadIdx.x;
  int xi = i % HH, yi = i / HH;
  float s = 0.f;
  for (int j = lane; j < NP; j += 64) {
    if (j == i) continue;
    int xj = j % HH, yj = j / HH;
    float dx = (float)(xi - xj), dy = (float)(yi - yj);
    s += __builtin_amdgcn_exp2f(-L2E8 * (dx * dx + dy * dy));
  }
  s = wave_sum(s);
  if (lane == 0) rsg[i] = 1.f / sqrtf(s);
}

// K5: bilateral row sums -> colors.w. LDS-tiled: block = 64 i's, 8 j-split waves.
__global__ __launch_bounds__(512) void k_rsb(float4* __restrict__ COL,
                                             const float2* __restrict__ XY) {
  __shared__ float S8[NP * 8];     // 53.8 KB
  __shared__ float Red2[8 * 64];
  const int nb = blockIdx.x / RSB_TILES;
  const int i0 = (blockIdx.x % RSB_TILES) * 64;
  const int tid = (int)threadIdx.x;
  const int lane = tid & 63, wv = tid >> 6;

  const float4* colb = COL + (size_t)nb * NP;
  for (int j = tid; j < NP; j += 512) {
    float4 c = colb[j];
    float2 xy = XY[j];
    *(float4*)&S8[j * 8]     = make_float4(c.x, c.y, c.z, 0.f);
    *(float4*)&S8[j * 8 + 4] = make_float4(xy.x, xy.y, 0.f, 0.f);
  }
  __syncthreads();

  const int i = i0 + lane;
  const int im = min(i, NP - 1);
  const float ci0 = S8[im * 8], ci1 = S8[im * 8 + 1], ci2 = S8[im * 8 + 2];
  const float xi = S8[im * 8 + 4], yi = S8[im * 8 + 5];

  float s = 0.f;
  for (int j = wv; j < NP; j += 8) {
    float4 a = *(const float4*)&S8[j * 8];
    float4 b = *(const float4*)&S8[j * 8 + 4];
    float dx = xi - b.x, dy = yi - b.y;
    float acc = dx * dx;
    acc = fmaf(dy, dy, acc);
    float e0 = ci0 - a.x, e1 = ci1 - a.y, e2 = ci2 - a.z;
    acc = fmaf(e0, e0, acc);
    acc = fmaf(e1, e1, acc);
    acc = fmaf(e2, e2, acc);
    s += __builtin_amdgcn_exp2f(-acc);
  }
  Red2[wv * 64 + lane] = s;
  __syncthreads();
  if (wv == 0 && i < NP) {
    float t = -1.0f;   // remove self term
    #pragma unroll
    for (int w = 0; w < 8; ++w) t += Red2[w * 64 + lane];
    ((float*)(COL + (size_t)nb * NP + i))[3] = 1.f / sqrtf(t);
  }
}

// K6: M[n][i][j] = 10*Kb_norm + 3*Kg_norm (bf16, diag 0), row stride KPAD.
// Round-4 structure: global/L1 loads, incremental coords, pack-2 stores.
// Pad cols [1696,1792) left unwritten (they multiply zeroed QB kbs).
__global__ __launch_bounds__(256) void k_buildM(const float4* __restrict__ COL,
                                                const float* __restrict__ rsg,
                                                ushort_t* __restrict__ M) {
  int row = blockIdx.x;     // [0, NPIX)
  int nb = row / NP, i = row % NP;
  float4 ci = COL[row];
  float xi = (float)(i % HH) * CS_XY, yi = (float)(i / HH) * CS_XY;
  float sb = 10.f * ci.w;
  float sg = 3.f * rsg[i];
  const float4* colb = COL + (size_t)nb * NP;
  uint_t* Mrow = (uint_t*)(M + ((size_t)nb * NROWS + i) * KPAD);

  const float XW = 40.5f * CS_XY;
  const float X41 = 41.0f * CS_XY;
  int j0 = 2 * (int)threadIdx.x;
  float x0 = (float)(j0 % HH) * CS_XY;
  float y0 = (float)(j0 / HH) * CS_XY;

  for (int p = (int)threadIdx.x; p < 848; p += 256) {
    int ja = 2 * p, jb = ja + 1;
    float x1 = x0 + CS_XY, y1 = y0;
    if (x1 > XW) { x1 = 0.f; y1 += CS_XY; }

    float va, vb;
    {
      int jc = min(ja, NP - 1);
      float4 cj = colb[jc];
      float dx = xi - x0, dy = yi - y0;
      float axy = fmaf(dy, dy, dx * dx);
      float e0 = ci.x - cj.x, e1 = ci.y - cj.y, e2 = ci.z - cj.z;
      float acc = axy;
      acc = fmaf(e0, e0, acc);
      acc = fmaf(e1, e1, acc);
      acc = fmaf(e2, e2, acc);
      va = __builtin_amdgcn_exp2f(-acc) * (sb * cj.w);
      if (axy < GATE) va = fmaf(__builtin_amdgcn_exp2f(-KGC * axy), sg * rsg[jc], va);
      if (ja >= NP || ja == i) va = 0.f;
    }
    {
      int jc = min(jb, NP - 1);
      float4 cj = colb[jc];
      float dx = xi - x1, dy = yi - y1;
      float axy = fmaf(dy, dy, dx * dx);
      float e0 = ci.x - cj.x, e1 = ci.y - cj.y, e2 = ci.z - cj.z;
      float acc = axy;
      acc = fmaf(e0, e0, acc);
      acc = fmaf(e1, e1, acc);
      acc = fmaf(e2, e2, acc);
      vb = __builtin_amdgcn_exp2f(-acc) * (sb * cj.w);
      if (axy < GATE) vb = fmaf(__builtin_amdgcn_exp2f(-KGC * axy), sg * rsg[jc], vb);
      if (jb >= NP || jb == i) vb = 0.f;
    }
    Mrow[p] = (uint_t)f32_to_bf16(va) | ((uint_t)f32_to_bf16(vb) << 16);

    x0 += 20.f * CS_XY; y0 += 12.f * CS_XY;
    if (x0 > XW) { x0 -= X41; y0 += CS_XY; }
  }
}

// K7: one mean-field iteration via MFMA + global_load_lds pipelining.
// 256 threads = 4 waves; wave w owns rows [t0+w*16, +16) over full K (no reduction).
// K in 7 chunks of 8 kb: A-tile 32 KB (XOR-swizzled 16B units) + B 16 KB staged by DMA.
__global__ __launch_bounds__(256) void k_iter(const ushort_t* __restrict__ M,
                                              const ushort_t* __restrict__ QBin,
                                              ushort_t* __restrict__ QBout,
                                              const float* __restrict__ LOGU,
                                              float* __restrict__ QF) {
  __shared__ ushort_t Abuf[64 * 256];   // 32 KB: [row64][col256], 16B-unit u at u^(row&7)
  __shared__ ushort_t Bbuf[8 * 1024];   // 16 KB: [kb8][2ct][64lane][8]
  const int nb = blockIdx.x / ITL;
  const int t0 = (blockIdx.x % ITL) * 64;
  const int tid = (int)threadIdx.x;
  const int lane = tid & 63;
  const int w = tid >> 6;               // 0..3
  const int mrow = lane & 15, quad = lane >> 4;

  const int rA = lane >> 5;             // DMA: row within pair
  const int uA = lane & 31;             // DMA: 16B unit within row

  f32x4 acc0 = {0.f, 0.f, 0.f, 0.f};    // ct0 (ch 0..15)
  f32x4 acc1 = {0.f, 0.f, 0.f, 0.f};    // ct1 (ch 16..20)

  const size_t Mrow0 = (size_t)(nb * NROWS + t0);
  const ushort_t* Qb = QBin + (size_t)nb * QB_BATCH;

  for (int kc = 0; kc < 7; ++kc) {
    // A DMA: 32 instr of 1 KB (2 rows each); wave w issues t = w*8..w*8+7
    #pragma unroll
    for (int t8 = 0; t8 < 8; ++t8) {
      int t = w * 8 + t8;
      int r = 2 * t + rA;
      int up = uA ^ (r & 7);
      const ushort_t* g = M + (Mrow0 + r) * KPAD + kc * 256 + up * 8;
      GLOAD_LDS16(g, Abuf + t * 512);
    }
    // B DMA: 16 instr of 1 KB; wave w issues t = w*4..w*4+3
    #pragma unroll
    for (int t4 = 0; t4 < 4; ++t4) {
      int t = w * 4 + t4;
      const ushort_t* g = Qb + (size_t)kc * 8192 + t * 512 + lane * 8;
      GLOAD_LDS16(g, Bbuf + t * 512);
    }
    __syncthreads();
    #pragma unroll
    for (int c = 0; c < 8; ++c) {
      short8 a  = *(const short8*)(Abuf + (w * 16 + mrow) * 256 +
                                   (((c * 4 + quad) ^ (mrow & 7)) * 8));
      short8 b0 = *(const short8*)(Bbuf + c * 1024 + lane * 8);
      short8 b1 = *(const short8*)(Bbuf + c * 1024 + 512 + lane * 8);
      acc0 = __builtin_amdgcn_mfma_f32_16x16x32_bf16(a, b0, acc0, 0, 0, 0);
      acc1 = __builtin_amdgcn_mfma_f32_16x16x32_bf16(a, b1, acc1, 0, 0, 0);
    }
    __syncthreads();
  }

  // per-wave epilogue (rows are exclusively this wave's)
  const bool c1ok = (mrow + 16) < NCH;
  #pragma unroll
  for (int reg = 0; reg < 4; ++reg) {
    int r = t0 + w * 16 + quad * 4 + reg;
    int rg = nb * NP + min(r, NP - 1);
    float tv0 = LOGU[(size_t)rg * QS + mrow] + acc0[reg];
    float tv1 = c1ok ? (LOGU[(size_t)rg * QS + 16 + mrow] + acc1[reg]) : -1e30f;
    float mx = fmaxf(tv0, tv1);
    mx = fmaxf(mx, __shfl_xor(mx, 1));
    mx = fmaxf(mx, __shfl_xor(mx, 2));
    mx = fmaxf(mx, __shfl_xor(mx, 4));
    mx = fmaxf(mx, __shfl_xor(mx, 8));
    float e0 = __expf(tv0 - mx);
    float e1 = c1ok ? __expf(tv1 - mx) : 0.f;
    float sm = e0 + e1;
    sm += __shfl_xor(sm, 1);
    sm += __shfl_xor(sm, 2);
    sm += __shfl_xor(sm, 4);
    sm += __shfl_xor(sm, 8);
    float rinv = 1.f / sm;
    if (r < NP) {
      int kb = r >> 5, kr = r & 31, q2 = kr >> 3, j = kr & 7;
      size_t sbo = (size_t)nb * QB_BATCH + (size_t)kb * 1024 + (q2 * 16 + mrow) * 8 + j;
      float q0 = e0 * rinv;
      QF[(size_t)(nb * NP + r) * QS + mrow] = q0;
      QBout[sbo] = f32_to_bf16(q0);
      if (c1ok) {
        float q1 = e1 * rinv;
        QF[(size_t)(nb * NP + r) * QS + 16 + mrow] = q1;
        QBout[sbo + 512] = f32_to_bf16(q1);
      }
    }
  }
}

// K8: per-pixel loss contribution, block-reduced partials
__global__ void k_loss(const float* __restrict__ Qf, const float* __restrict__ P,
                       float* __restrict__ part) {
  int t = blockIdx.x * blockDim.x + threadIdx.x;
  float s = 0.f;
  if (t < NPIX) {
    const float* q = Qf + (size_t)t * QS;
    const float* p = P + (size_t)t * QS;
    float qv[NCH];
    float qsum = 0.f;
    #pragma unroll
    for (int c = 0; c < NCH; ++c) { qv[c] = fmaxf(q[c], EPSV); qsum += qv[c]; }
    float r = 1.f / qsum;
    #pragma unroll
    for (int c = 0; c < NCH; ++c) {
      float qs = qv[c] * r;
      float ratio = fminf(fmaxf(qs / p[c], 0.05f), 20.0f);
      s += qs * logf(ratio);
    }
  }
  __shared__ float red[256];
  red[threadIdx.x] = s;
  __syncthreads();
  for (int st = 128; st > 0; st >>= 1) {
    if ((int)threadIdx.x < st) red[threadIdx.x] += red[threadIdx.x + st];
    __syncthreads();
  }
  if (threadIdx.x == 0) part[blockIdx.x] = red[0];
}

// K9: final reduction -> d_out[0]
__global__ void k_final(const float* __restrict__ part, float* __restrict__ out) {
  float s = 0.f;
  for (int k = threadIdx.x; k < LOSS_BLOCKS; k += 64) s += part[k];
  s = wave_sum(s);
  if (threadIdx.x == 0) out[0] = s / (float)NPIX;
}

}  // namespace

extern "C" void kernel_launch(void* const* d_in, const int* in_sizes, int n_in,
                              void* d_out, int out_size, void* d_ws, size_t ws_size,
                              hipStream_t stream) {
  const float* images  = (const float*)d_in[0];   // (16,3,321,321) fp32
  const float* predict = (const float*)d_in[1];   // (16,21,41,41) fp32
  float* out = (float*)d_out;
  float* ws = (float*)d_ws;

  float*  W    = ws + OFF_W;
  float*  RX   = ws + OFF_RX;
  float4* COL  = (float4*)(ws + OFF_COL);
  float*  P    = ws + OFF_P;
  float*  LOGU = ws + OFF_LOGU;
  float*  QF   = ws + OFF_QF;
  float*  RSG  = ws + OFF_RSG;
  float2* XY   = (float2*)(ws + OFF_XY);
  float*  PART = ws + OFF_PART;
  ushort_t* QB_A = (ushort_t*)(ws + OFF_QB);
  ushort_t* QB_B = QB_A + (size_t)QB_BUF;
  ushort_t* M    = (ushort_t*)(ws + OFF_M);

  hipLaunchKernelGGL(k_zero, dim3((unsigned)((QB_ZERO_DWORDS + 255) / 256)), dim3(256), 0,
                     stream, (uint_t*)QB_A);
  hipLaunchKernelGGL(k_weights, dim3(1), dim3(64), 0, stream, W);
  hipLaunchKernelGGL(k_xy, dim3((NP + 255) / 256), dim3(256), 0, stream, XY);
  hipLaunchKernelGGL(k_resize_x, dim3((RXN + 255) / 256), dim3(256), 0, stream, images, W, RX);
  hipLaunchKernelGGL(k_resize_y, dim3(LOSS_BLOCKS), dim3(256), 0, stream, RX, W, (float*)COL);
  hipLaunchKernelGGL(k_probs, dim3(LOSS_BLOCKS), dim3(256), 0, stream, predict, P, LOGU, QB_A);
  hipLaunchKernelGGL(k_rsg, dim3(NP), dim3(64), 0, stream, RSG);
  hipLaunchKernelGGL(k_rsb, dim3(NBATCH * RSB_TILES), dim3(512), 0, stream, COL, XY);
  hipLaunchKernelGGL(k_buildM, dim3(NPIX), dim3(256), 0, stream, COL, RSG, M);

  const ushort_t* qbin = QB_A;
  ushort_t* qbout = QB_B;
  for (int it = 0; it < 10; ++it) {
    hipLaunchKernelGGL(k_iter, dim3(NBATCH * ITL), dim3(256), 0, stream,
                       M, qbin, qbout, LOGU, QF);
    const ushort_t* t = qbout; qbout = (ushort_t*)qbin; qbin = t;
  }
  hipLaunchKernelGGL(k_loss, dim3(LOSS_BLOCKS), dim3(256), 0, stream, QF, P, PART);
  hipLaunchKernelGGL(k_final, dim3(1), dim3(64), 0, stream, PART, out);
}

// Round 7
// 332.174 us; speedup vs baseline: 2.6083x; 1.2564x over previous
//
#include <hip/hip_runtime.h>
#include <math.h>

namespace {

typedef unsigned short ushort_t;
typedef unsigned int uint_t;
typedef unsigned char uchar_t;
typedef __attribute__((ext_vector_type(4))) float f32x4;

constexpr int NBATCH = 16;
constexpr int NCH    = 21;
constexpr int HH     = 41;
constexpr int NP     = HH * HH;       // 1681 pixels
constexpr int IW     = 321;           // input image H=W
constexpr int QS     = 32;            // padded channel stride for P/LOGU/QF
constexpr float EPSV = 1e-5f;

constexpr int NROWS  = 1696;          // M rows per batch
constexpr int KPAD   = 1792;          // M cols (bytes) padded to 56*32
constexpr int ITL    = 27;            // 64-row tiles per batch
constexpr int NPIX   = NBATCH * NP;             // 26896
constexpr int LOSS_BLOCKS = (NPIX + 255) / 256; // 106
constexpr int RSB_TILES = (NP + 63) / 64;       // 27

// B-fragment-linear Q storage (fp8): per batch [56 kb][2 ct][64 lane][8 B]
constexpr int QB_BATCH = 56 * 2 * 512;           // 57344 bytes per batch
constexpr int QB_BUF   = NBATCH * QB_BATCH;      // 917504 bytes per buffer
constexpr int RXN = NBATCH * 3 * IW * HH;        // 631728

constexpr float CS_COLOR = 0.06533245f;   // sqrt(log2(e)/338)
constexpr float CS_XY    = 0.12739827f;   // sqrt(0.01125*log2(e))
constexpr float KGC      = 711.111111f;   // exp(-8*d2)=exp2(-KGC*axy)
constexpr float L2E8     = 11.5415603f;   // 8*log2(e)
constexpr float GATE     = 0.138f;        // axy gate ~ d2<=8

// workspace offsets in floats
constexpr size_t OFF_W    = 0;                   // 13184
constexpr size_t OFF_RX   = 13184;               // 631744
constexpr size_t OFF_COL  = 644928;              // scaled colors+rsb.w [npix][4]
constexpr size_t OFF_P    = 752512;              // 860672
constexpr size_t OFF_LOGU = 1613184;             // 860672
constexpr size_t OFF_QF   = 2473856;             // 860672
constexpr size_t OFF_RSG  = 3334528;             // 1728
constexpr size_t OFF_XY   = 3336256;             // 3456
constexpr size_t OFF_PART = 3339712;             // 256
constexpr size_t OFF_QB   = 3339968;             // 2 fp8 buffers = 458752 floats
constexpr size_t OFF_M    = 3798720;             // fp8 M [16][1696][1792 B]
// total = 3798720 + 12156928 = 15,955,648 floats ~ 63.8 MB

constexpr size_t QB_ZERO_DWORDS = 458752;        // both QB buffers, dwords

#define GLOAD_LDS16(g, l)                                                              \
  __builtin_amdgcn_global_load_lds((const __attribute__((address_space(1))) uint_t*)(g), \
                                   (__attribute__((address_space(3))) uint_t*)(l), 16, 0, 0)

__device__ __forceinline__ float wave_sum(float v) {
  #pragma unroll
  for (int off = 32; off > 0; off >>= 1) v += __shfl_down(v, off, 64);
  return v;
}

__device__ __forceinline__ uchar_t f32_to_fp8(float f) {
  return (uchar_t)(__builtin_amdgcn_cvt_pk_fp8_f32(f, f, 0, false) & 0xff);
}

__global__ void k_zero(uint_t* __restrict__ p) {
  size_t t = (size_t)blockIdx.x * blockDim.x + threadIdx.x;
  if (t < QB_ZERO_DWORDS) p[t] = 0u;
}

// K1: jax.image.resize 'linear' (antialias) weight matrix, 321 -> 41.
__global__ void k_weights(float* __restrict__ W) {
  int o = threadIdx.x;
  if (o >= HH) return;
  const float inv = (float)IW / (float)HH;
  float s = (o + 0.5f) * inv - 0.5f;
  float tot = 0.f;
  for (int i = 0; i < IW; ++i) {
    float x = fabsf(s - (float)i) / inv;
    tot += fmaxf(0.f, 1.f - x);
  }
  float r = 1.f / tot;
  for (int i = 0; i < IW; ++i) {
    float x = fabsf(s - (float)i) / inv;
    W[o * IW + i] = fmaxf(0.f, 1.f - x) * r;
  }
}

__global__ void k_xy(float2* __restrict__ XY) {
  int j = blockIdx.x * blockDim.x + threadIdx.x;
  if (j >= NP) return;
  XY[j] = make_float2((float)(j % HH) * CS_XY, (float)(j / HH) * CS_XY);
}

// K2a: separable resize, x pass
__global__ void k_resize_x(const float* __restrict__ img, const float* __restrict__ W,
                           float* __restrict__ RX) {
  int t = blockIdx.x * blockDim.x + threadIdx.x;
  if (t >= RXN) return;
  int xo = t % HH;
  int rest = t / HH;
  int y = rest % IW;
  int nc = rest / IW;
  const float inv = (float)IW / (float)HH;
  float sx = (xo + 0.5f) * inv - 0.5f;
  int xlo = max(0, (int)ceilf(sx - inv)), xhi = min(IW - 1, (int)floorf(sx + inv));
  const float* base = img + ((size_t)nc * IW + y) * IW;
  const float* wr = W + xo * IW;
  float a = 0.f;
  for (int ix = xlo; ix <= xhi; ++ix) a += wr[ix] * base[ix];
  RX[t] = a;
}

// K2b: y pass -> SCALED colors [n][p][4]
__global__ void k_resize_y(const float* __restrict__ RX, const float* __restrict__ W,
                           float* __restrict__ colors) {
  int t = blockIdx.x * blockDim.x + threadIdx.x;
  if (t >= NPIX) return;
  int nb = t / NP, p = t % NP;
  int yo = p / HH, xo = p % HH;
  const float inv = (float)IW / (float)HH;
  float sy = (yo + 0.5f) * inv - 0.5f;
  int ylo = max(0, (int)ceilf(sy - inv)), yhi = min(IW - 1, (int)floorf(sy + inv));
  const float* wr = W + yo * IW;
  float a0 = 0.f, a1 = 0.f, a2 = 0.f;
  const float* b0 = RX + (size_t)(nb * 3 + 0) * IW * HH + xo;
  const float* b1 = RX + (size_t)(nb * 3 + 1) * IW * HH + xo;
  const float* b2 = RX + (size_t)(nb * 3 + 2) * IW * HH + xo;
  for (int iy = ylo; iy <= yhi; ++iy) {
    float wy = wr[iy];
    a0 += wy * b0[(size_t)iy * HH];
    a1 += wy * b1[(size_t)iy * HH];
    a2 += wy * b2[(size_t)iy * HH];
  }
  float* c = colors + (size_t)t * 4;
  c[0] = a0 * CS_COLOR; c[1] = a1 * CS_COLOR; c[2] = a2 * CS_COLOR; c[3] = 0.f;
}

// K3: clamped channel softmax -> P, LOGU, initial fp8 B-fragments
__global__ void k_probs(const float* __restrict__ pred, float* __restrict__ P,
                        float* __restrict__ LOGU, uchar_t* __restrict__ QB) {
  int t = blockIdx.x * blockDim.x + threadIdx.x;
  if (t >= NPIX) return;
  int nb = t / NP, i = t % NP;
  const float* src = pred + (size_t)nb * NCH * NP + i;
  float v[NCH];
  float m = -1e30f;
  #pragma unroll
  for (int c = 0; c < NCH; ++c) { v[c] = src[(size_t)c * NP]; m = fmaxf(m, v[c]); }
  float s = 0.f;
  #pragma unroll
  for (int c = 0; c < NCH; ++c) { v[c] = expf(v[c] - m); s += v[c]; }
  float r = 1.f / s;
  float s2 = 0.f;
  #pragma unroll
  for (int c = 0; c < NCH; ++c) { v[c] = fminf(fmaxf(v[c] * r, EPSV), 1.0f); s2 += v[c]; }
  float r2 = 1.f / s2;
  float* dp = P + (size_t)t * QS;
  float* dl = LOGU + (size_t)t * QS;
  int kb = i >> 5, kr = i & 31, q2 = kr >> 3, j = kr & 7;
  size_t sb = (size_t)nb * QB_BATCH + (size_t)kb * 1024 + j;
  #pragma unroll
  for (int c = 0; c < NCH; ++c) {
    float p = v[c] * r2;
    dp[c] = p; dl[c] = logf(p);
    int ct = c >> 4;
    QB[sb + (size_t)ct * 512 + (q2 * 16 + (c & 15)) * 8] = f32_to_fp8(p);
  }
}

// K4: Gaussian row sums
__global__ void k_rsg(float* __restrict__ rsg) {
  int i = blockIdx.x;
  int lane = threadIdx.x;
  int xi = i % HH, yi = i / HH;
  float s = 0.f;
  for (int j = lane; j < NP; j += 64) {
    if (j == i) continue;
    int xj = j % HH, yj = j / HH;
    float dx = (float)(xi - xj), dy = (float)(yi - yj);
    s += __builtin_amdgcn_exp2f(-L2E8 * (dx * dx + dy * dy));
  }
  s = wave_sum(s);
  if (lane == 0) rsg[i] = 1.f / sqrtf(s);
}

// K5: bilateral row sums -> colors.w (LDS-tiled)
__global__ __launch_bounds__(512) void k_rsb(float4* __restrict__ COL,
                                             const float2* __restrict__ XY) {
  __shared__ float S8[NP * 8];
  __shared__ float Red2[8 * 64];
  const int nb = blockIdx.x / RSB_TILES;
  const int i0 = (blockIdx.x % RSB_TILES) * 64;
  const int tid = (int)threadIdx.x;
  const int lane = tid & 63, wv = tid >> 6;

  const float4* colb = COL + (size_t)nb * NP;
  for (int j = tid; j < NP; j += 512) {
    float4 c = colb[j];
    float2 xy = XY[j];
    *(float4*)&S8[j * 8]     = make_float4(c.x, c.y, c.z, 0.f);
    *(float4*)&S8[j * 8 + 4] = make_float4(xy.x, xy.y, 0.f, 0.f);
  }
  __syncthreads();

  const int i = i0 + lane;
  const int im = min(i, NP - 1);
  const float ci0 = S8[im * 8], ci1 = S8[im * 8 + 1], ci2 = S8[im * 8 + 2];
  const float xi = S8[im * 8 + 4], yi = S8[im * 8 + 5];

  float s = 0.f;
  for (int j = wv; j < NP; j += 8) {
    float4 a = *(const float4*)&S8[j * 8];
    float4 b = *(const float4*)&S8[j * 8 + 4];
    float dx = xi - b.x, dy = yi - b.y;
    float acc = dx * dx;
    acc = fmaf(dy, dy, acc);
    float e0 = ci0 - a.x, e1 = ci1 - a.y, e2 = ci2 - a.z;
    acc = fmaf(e0, e0, acc);
    acc = fmaf(e1, e1, acc);
    acc = fmaf(e2, e2, acc);
    s += __builtin_amdgcn_exp2f(-acc);
  }
  Red2[wv * 64 + lane] = s;
  __syncthreads();
  if (wv == 0 && i < NP) {
    float t = -1.0f;
    #pragma unroll
    for (int w = 0; w < 8; ++w) t += Red2[w * 64 + lane];
    ((float*)(COL + (size_t)nb * NP + i))[3] = 1.f / sqrtf(t);
  }
}

// K6: M[n][i][j] = 10*Kb_norm + 3*Kg_norm (fp8 e4m3, diag 0), row stride KPAD bytes.
// Incremental coords, pack-4 dword stores. Cols [1696,1792) unwritten (B pads zero).
__global__ __launch_bounds__(256) void k_buildM(const float4* __restrict__ COL,
                                                const float* __restrict__ rsg,
                                                uchar_t* __restrict__ M) {
  int row = blockIdx.x;     // [0, NPIX)
  int nb = row / NP, i = row % NP;
  float4 ci = COL[row];
  float xi = (float)(i % HH) * CS_XY, yi = (float)(i / HH) * CS_XY;
  float sb = 10.f * ci.w;
  float sg = 3.f * rsg[i];
  const float4* colb = COL + (size_t)nb * NP;
  uint_t* Mrow = (uint_t*)(M + ((size_t)nb * NROWS + i) * KPAD);

  const float XW = 40.5f * CS_XY;
  const float X41 = 41.0f * CS_XY;
  int j0 = 4 * (int)threadIdx.x;
  float x = (float)(j0 % HH) * CS_XY;
  float y = (float)(j0 / HH) * CS_XY;

  for (int p = (int)threadIdx.x; p < 424; p += 256) {
    int jj = 4 * p;
    float xx = x, yy = y;
    float v[4];
    #pragma unroll
    for (int e = 0; e < 4; ++e) {
      int je = jj + e;
      int jc = min(je, NP - 1);
      float4 cj = colb[jc];
      float dx = xi - xx, dy = yi - yy;
      float axy = fmaf(dy, dy, dx * dx);
      float e0 = ci.x - cj.x, e1 = ci.y - cj.y, e2 = ci.z - cj.z;
      float acc = axy;
      acc = fmaf(e0, e0, acc);
      acc = fmaf(e1, e1, acc);
      acc = fmaf(e2, e2, acc);
      float val = __builtin_amdgcn_exp2f(-acc) * (sb * cj.w);
      if (axy < GATE) val = fmaf(__builtin_amdgcn_exp2f(-KGC * axy), sg * rsg[jc], val);
      v[e] = (je < NP && je != i) ? val : 0.f;
      xx += CS_XY;
      if (xx > XW) { xx = 0.f; yy += CS_XY; }
    }
    uint_t wrd = __builtin_amdgcn_cvt_pk_fp8_f32(v[0], v[1], 0, false);
    wrd = __builtin_amdgcn_cvt_pk_fp8_f32(v[2], v[3], (int)wrd, true);
    Mrow[p] = wrd;

    // advance 1024 pixels: x += 40, y += 24 (+wrap)
    x += 40.f * CS_XY; y += 24.f * CS_XY;
    if (x > XW) { x -= X41; y += CS_XY; }
  }
}

// K7: one mean-field iteration via fp8 MFMA + global_load_lds.
// 256 threads = 4 waves; wave w owns rows [t0+w*16,+16) over full K.
// Grid swizzle: blockIdx = tile*16 + nb  =>  batch nb pinned to XCD nb%8 (L2 locality).
__global__ __launch_bounds__(256) void k_iter(const uchar_t* __restrict__ M,
                                              const uchar_t* __restrict__ QBin,
                                              uchar_t* __restrict__ QBout,
                                              const float* __restrict__ LOGU,
                                              float* __restrict__ QF) {
  __shared__ uchar_t Abuf[64 * 256];   // 16 KB: [row][256 B], 16B unit u at u^(r&7)
  __shared__ uchar_t Bbuf[8 * 1024];   // 8 KB: [kb8][2ct][64lane][8 B]
  const int nb = blockIdx.x & 15;
  const int t0 = (blockIdx.x >> 4) * 64;
  const int tid = (int)threadIdx.x;
  const int lane = tid & 63;
  const int w = tid >> 6;               // 0..3
  const int mrow = lane & 15, quad = lane >> 4;

  f32x4 acc0 = {0.f, 0.f, 0.f, 0.f};    // ch 0..15
  f32x4 acc1 = {0.f, 0.f, 0.f, 0.f};    // ch 16..20

  const size_t Mrow0 = (size_t)(nb * NROWS + t0);
  const uchar_t* Qb = QBin + (size_t)nb * QB_BATCH;

  for (int kc = 0; kc < 7; ++kc) {
    // A DMA: 16 instr of 1 KB (4 rows each); wave w issues t = w*4..w*4+3
    #pragma unroll
    for (int t4 = 0; t4 < 4; ++t4) {
      int t = w * 4 + t4;
      int r = t * 4 + (lane >> 4);
      int ug = (lane & 15) ^ (r & 7);
      const uchar_t* g = M + (Mrow0 + r) * KPAD + kc * 256 + ug * 16;
      GLOAD_LDS16(g, Abuf + t * 1024);
    }
    // B DMA: 8 instr of 1 KB; wave w issues t = w*2..w*2+1
    #pragma unroll
    for (int t2 = 0; t2 < 2; ++t2) {
      int t = w * 2 + t2;
      const uchar_t* g = Qb + (size_t)kc * 8192 + t * 1024 + lane * 16;
      GLOAD_LDS16(g, Bbuf + t * 1024);
    }
    __syncthreads();
    #pragma unroll
    for (int c = 0; c < 8; ++c) {
      long a = *(const long*)(Abuf + (w * 16 + mrow) * 256 +
                              (((c * 2 + (quad >> 1)) ^ (mrow & 7)) * 16) + (quad & 1) * 8);
      long b0 = *(const long*)(Bbuf + c * 1024 + lane * 8);
      long b1 = *(const long*)(Bbuf + c * 1024 + 512 + lane * 8);
      acc0 = __builtin_amdgcn_mfma_f32_16x16x32_fp8_fp8(a, b0, acc0, 0, 0, 0);
      acc1 = __builtin_amdgcn_mfma_f32_16x16x32_fp8_fp8(a, b1, acc1, 0, 0, 0);
    }
    __syncthreads();
  }

  const bool c1ok = (mrow + 16) < NCH;
  #pragma unroll
  for (int reg = 0; reg < 4; ++reg) {
    int r = t0 + w * 16 + quad * 4 + reg;
    int rg = nb * NP + min(r, NP - 1);
    float tv0 = LOGU[(size_t)rg * QS + mrow] + acc0[reg];
    float tv1 = c1ok ? (LOGU[(size_t)rg * QS + 16 + mrow] + acc1[reg]) : -1e30f;
    float mx = fmaxf(tv0, tv1);
    mx = fmaxf(mx, __shfl_xor(mx, 1));
    mx = fmaxf(mx, __shfl_xor(mx, 2));
    mx = fmaxf(mx, __shfl_xor(mx, 4));
    mx = fmaxf(mx, __shfl_xor(mx, 8));
    float e0 = __expf(tv0 - mx);
    float e1 = c1ok ? __expf(tv1 - mx) : 0.f;
    float sm = e0 + e1;
    sm += __shfl_xor(sm, 1);
    sm += __shfl_xor(sm, 2);
    sm += __shfl_xor(sm, 4);
    sm += __shfl_xor(sm, 8);
    float rinv = 1.f / sm;
    if (r < NP) {
      int kb = r >> 5, kr = r & 31, q2 = kr >> 3, j = kr & 7;
      size_t sbo = (size_t)nb * QB_BATCH + (size_t)kb * 1024 + (q2 * 16 + mrow) * 8 + j;
      float q0 = e0 * rinv;
      QF[(size_t)(nb * NP + r) * QS + mrow] = q0;
      QBout[sbo] = f32_to_fp8(q0);
      if (c1ok) {
        float q1 = e1 * rinv;
        QF[(size_t)(nb * NP + r) * QS + 16 + mrow] = q1;
        QBout[sbo + 512] = f32_to_fp8(q1);
      }
    }
  }
}

// K8: per-pixel loss contribution
__global__ void k_loss(const float* __restrict__ Qf, const float* __restrict__ P,
                       float* __restrict__ part) {
  int t = blockIdx.x * blockDim.x + threadIdx.x;
  float s = 0.f;
  if (t < NPIX) {
    const float* q = Qf + (size_t)t * QS;
    const float* p = P + (size_t)t * QS;
    float qv[NCH];
    float qsum = 0.f;
    #pragma unroll
    for (int c = 0; c < NCH; ++c) { qv[c] = fmaxf(q[c], EPSV); qsum += qv[c]; }
    float r = 1.f / qsum;
    #pragma unroll
    for (int c = 0; c < NCH; ++c) {
      float qs = qv[c] * r;
      float ratio = fminf(fmaxf(qs / p[c], 0.05f), 20.0f);
      s += qs * logf(ratio);
    }
  }
  __shared__ float red[256];
  red[threadIdx.x] = s;
  __syncthreads();
  for (int st = 128; st > 0; st >>= 1) {
    if ((int)threadIdx.x < st) red[threadIdx.x] += red[threadIdx.x + st];
    __syncthreads();
  }
  if (threadIdx.x == 0) part[blockIdx.x] = red[0];
}

// K9: final reduction -> d_out[0]
__global__ void k_final(const float* __restrict__ part, float* __restrict__ out) {
  float s = 0.f;
  for (int k = threadIdx.x; k < LOSS_BLOCKS; k += 64) s += part[k];
  s = wave_sum(s);
  if (threadIdx.x == 0) out[0] = s / (float)NPIX;
}

}  // namespace

extern "C" void kernel_launch(void* const* d_in, const int* in_sizes, int n_in,
                              void* d_out, int out_size, void* d_ws, size_t ws_size,
                              hipStream_t stream) {
  const float* images  = (const float*)d_in[0];   // (16,3,321,321) fp32
  const float* predict = (const float*)d_in[1];   // (16,21,41,41) fp32
  float* out = (float*)d_out;
  float* ws = (float*)d_ws;

  float*  W    = ws + OFF_W;
  float*  RX   = ws + OFF_RX;
  float4* COL  = (float4*)(ws + OFF_COL);
  float*  P    = ws + OFF_P;
  float*  LOGU = ws + OFF_LOGU;
  float*  QF   = ws + OFF_QF;
  float*  RSG  = ws + OFF_RSG;
  float2* XY   = (float2*)(ws + OFF_XY);
  float*  PART = ws + OFF_PART;
  uchar_t* QB_A = (uchar_t*)(ws + OFF_QB);
  uchar_t* QB_B = QB_A + (size_t)QB_BUF;
  uchar_t* M    = (uchar_t*)(ws + OFF_M);

  hipLaunchKernelGGL(k_zero, dim3((unsigned)((QB_ZERO_DWORDS + 255) / 256)), dim3(256), 0,
                     stream, (uint_t*)QB_A);
  hipLaunchKernelGGL(k_weights, dim3(1), dim3(64), 0, stream, W);
  hipLaunchKernelGGL(k_xy, dim3((NP + 255) / 256), dim3(256), 0, stream, XY);
  hipLaunchKernelGGL(k_resize_x, dim3((RXN + 255) / 256), dim3(256), 0, stream, images, W, RX);
  hipLaunchKernelGGL(k_resize_y, dim3(LOSS_BLOCKS), dim3(256), 0, stream, RX, W, (float*)COL);
  hipLaunchKernelGGL(k_probs, dim3(LOSS_BLOCKS), dim3(256), 0, stream, predict, P, LOGU, QB_A);
  hipLaunchKernelGGL(k_rsg, dim3(NP), dim3(64), 0, stream, RSG);
  hipLaunchKernelGGL(k_rsb, dim3(NBATCH * RSB_TILES), dim3(512), 0, stream, COL, XY);
  hipLaunchKernelGGL(k_buildM, dim3(NPIX), dim3(256), 0, stream, COL, RSG, M);

  const uchar_t* qbin = QB_A;
  uchar_t* qbout = QB_B;
  for (int it = 0; it < 10; ++it) {
    hipLaunchKernelGGL(k_iter, dim3(NBATCH * ITL), dim3(256), 0, stream,
                       M, qbin, qbout, LOGU, QF);
    const uchar_t* t = qbout; qbout = (uchar_t*)qbin; qbin = t;
  }
  hipLaunchKernelGGL(k_loss, dim3(LOSS_BLOCKS), dim3(256), 0, stream, QF, P, PART);
  hipLaunchKernelGGL(k_final, dim3(1), dim3(64), 0, stream, PART, out);
}